// Round 2
// baseline (1014.753 us; speedup 1.0000x reference)
//
#include <hip/hip_runtime.h>

// ---------------------------------------------------------------------------
// RPN forward: conv3x3(512->512)+relu, 1x1 heads (18 cls, 36 bbox),
// anchor decode + clip, softmax score, greedy NMS (0.7), keep-masked boxes.
// All decision math in fp32 with contraction OFF to track the numpy reference.
// R2: nms_scan rewritten — alive-only chunked column ORs (register-resident),
//     no 256-VGPR prefetch arrays (R1 version spilled them to scratch: 517us).
// ---------------------------------------------------------------------------

#define NBATCH 4
#define HWDIM  25
#define NPOS   625            // 25*25
#define NM     2500           // NBATCH*NPOS
#define CIN    512
#define NANCH  5625           // NPOS*9
#define NW     88             // ceil(NANCH/64)

struct BaseAnchors { float x1[9], y1[9], x2[9], y2[9]; };

__device__ __forceinline__ unsigned long long bcast64(unsigned long long v, int lane) {
  unsigned int lo = (unsigned int)v;
  unsigned int hi = (unsigned int)(v >> 32);
  lo = (unsigned int)__builtin_amdgcn_readlane((int)lo, lane);
  hi = (unsigned int)__builtin_amdgcn_readlane((int)hi, lane);
  return (((unsigned long long)hi) << 32) | (unsigned long long)lo;
}

// --------------------------- prep: transposes ------------------------------

// f[b][c][pos] -> fm[b*625+pos][c]
__global__ void transpose_features(const float* __restrict__ f, float* __restrict__ fm) {
  __shared__ float tile[32][33];
  int b  = blockIdx.z;
  int p0 = blockIdx.x * 32;
  int c0 = blockIdx.y * 32;
  int tx = threadIdx.x, ty = threadIdx.y;  // (32, 8)
#pragma unroll
  for (int j = 0; j < 4; j++) {
    int c = c0 + ty + j * 8;
    int p = p0 + tx;
    if (p < NPOS) tile[ty + j * 8][tx] = f[((size_t)(b * CIN + c)) * NPOS + p];
  }
  __syncthreads();
#pragma unroll
  for (int j = 0; j < 4; j++) {
    int p = p0 + ty + j * 8;
    int c = c0 + tx;
    if (p < NPOS) fm[((size_t)(b * NPOS + p)) * CIN + c] = tile[tx][ty + j * 8];
  }
}

// conv_w[o][c][tap] -> Wt[tap][c][o]
__global__ __launch_bounds__(256) void transpose_weights(const float* __restrict__ cw,
                                                         float* __restrict__ Wt) {
  __shared__ float tile[32][289];
  int o0 = blockIdx.x * 32, c0 = blockIdx.y * 32;
  int tid = threadIdx.x;
#pragma unroll
  for (int j = 0; j < 36; j++) {
    int idx = tid + j * 256;            // 0..9215
    int o = idx / 288, kk = idx % 288;  // kk = c_rel*9 + tap
    tile[o][kk] = cw[((size_t)(o0 + o)) * 4608 + c0 * 9 + kk];
  }
  __syncthreads();
  int ol = tid & 31, pg = tid >> 5;  // 0..7
#pragma unroll
  for (int j = 0; j < 36; j++) {
    int pair = pg + j * 8;  // 0..287 == c_rel*9 + tap
    int c = pair / 9, tap = pair % 9;
    Wt[((size_t)tap * CIN + (c0 + c)) * 512 + o0 + ol] = tile[ol][pair];
  }
}

// combined 1x1 head weights: Wco[c][o] (o: 0..17 cls, 18..53 bbox, 54..63 zero)
__global__ void build_wco(const float* __restrict__ clsw, const float* __restrict__ clsb,
                          const float* __restrict__ bw, const float* __restrict__ bbb,
                          float* __restrict__ Wco, float* __restrict__ bco) {
  int idx = blockIdx.x * 256 + threadIdx.x;
  if (idx < 512 * 64) {
    int c = idx >> 6, o = idx & 63;
    float v = 0.f;
    if (o < 18) v = clsw[o * 512 + c];
    else if (o < 54) v = bw[(o - 18) * 512 + c];
    Wco[idx] = v;
  }
  if (idx < 64) {
    float v = 0.f;
    if (idx < 18) v = clsb[idx];
    else if (idx < 54) v = bbb[idx - 18];
    bco[idx] = v;
  }
}

// --------------------------- conv3x3 implicit GEMM -------------------------
// grid (40, 8, 3): 64 m-rows x 64 o-cols per block, part = 3 taps (dy fixed).
// Writes partial sums (no bias/relu) to xp[part][m][o].
__global__ __launch_bounds__(256) void conv_gemm(const float* __restrict__ fm,
                                                 const float* __restrict__ Wt,
                                                 float* __restrict__ xp) {
  __shared__ __align__(16) float At[32][68];
  __shared__ __align__(16) float Bt[32][64];
  int tid = threadIdx.x;
  int m0 = blockIdx.x << 6;
  int o0 = blockIdx.y << 6;
  int part = blockIdx.z;  // 0..2 -> dy = part-1
  int ti = tid >> 4, tj = tid & 15;   // compute tile 4x4
  int si = tid >> 2, sq = tid & 3;    // A staging: row si, col quad sq
  int skk = tid >> 3, sr = tid & 7;   // B staging: k-row skk, col oct sr
  float acc[4][4] = {{0.f}};

  int m = m0 + si;
  bool mv = m < NM;
  int mm = mv ? m : 0;
  int bb = mm / NPOS, rem = mm % NPOS;
  int hh = rem / HWDIM, ww = rem % HWDIM;
  int dy = part - 1;

  for (int tt = 0; tt < 3; tt++) {
    int tap = part * 3 + tt;
    int dx = tt - 1;
    int h2 = hh + dy, w2 = ww + dx;
    bool av = mv && ((unsigned)h2 < (unsigned)HWDIM) && ((unsigned)w2 < (unsigned)HWDIM);
    const float* arow = fm + (((size_t)(bb * NPOS + h2 * HWDIM + w2)) << 9);
    const float* bbase = Wt + (((size_t)tap) << 18) + o0;
    for (int c0 = 0; c0 < CIN; c0 += 32) {
      __syncthreads();
      float4 a0 = make_float4(0.f, 0.f, 0.f, 0.f), a1 = a0;
      if (av) {
        a0 = *(const float4*)(arow + c0 + (sq << 2));
        a1 = *(const float4*)(arow + c0 + 16 + (sq << 2));
      }
      int kb = sq << 2;
      At[kb + 0][si] = a0.x; At[kb + 1][si] = a0.y; At[kb + 2][si] = a0.z; At[kb + 3][si] = a0.w;
      At[kb + 16][si] = a1.x; At[kb + 17][si] = a1.y; At[kb + 18][si] = a1.z; At[kb + 19][si] = a1.w;
      const float* bp = bbase + (((size_t)(c0 + skk)) << 9);
      *(float4*)&Bt[skk][sr << 2] = *(const float4*)(bp + (sr << 2));
      *(float4*)&Bt[skk][32 + (sr << 2)] = *(const float4*)(bp + 32 + (sr << 2));
      __syncthreads();
#pragma unroll
      for (int kk = 0; kk < 32; kk++) {
        float4 avv = *(const float4*)&At[kk][ti << 2];
        float4 bvv = *(const float4*)&Bt[kk][tj << 2];
        float a_[4] = {avv.x, avv.y, avv.z, avv.w};
        float b_[4] = {bvv.x, bvv.y, bvv.z, bvv.w};
#pragma unroll
        for (int u = 0; u < 4; u++)
#pragma unroll
          for (int v = 0; v < 4; v++) acc[u][v] += a_[u] * b_[v];
      }
    }
  }
  float* outp = xp + (size_t)part * (NM * 512);
#pragma unroll
  for (int u = 0; u < 4; u++) {
    int mr = m0 + (ti << 2) + u;
    if (mr < NM) {
      float4 r = make_float4(acc[u][0], acc[u][1], acc[u][2], acc[u][3]);
      *(float4*)(outp + (((size_t)mr) << 9) + o0 + (tj << 2)) = r;
    }
  }
}

// x2 = relu(xp0+xp1+xp2+bias)
__global__ void combine_relu(const float* __restrict__ xp, const float* __restrict__ bias,
                             float* __restrict__ x2) {
  int i4 = blockIdx.x * 256 + threadIdx.x;  // over 320000 float4s
  if (i4 >= NM * 128) return;
  float4 p0 = *(const float4*)(xp + (size_t)i4 * 4);
  float4 p1 = *(const float4*)(xp + (size_t)(NM * 512) + (size_t)i4 * 4);
  float4 p2 = *(const float4*)(xp + (size_t)(2 * NM * 512) + (size_t)i4 * 4);
  float4 bb = *(const float4*)(bias + (i4 & 127) * 4);
  float4 r;
  r.x = fmaxf(p0.x + p1.x + p2.x + bb.x, 0.f);
  r.y = fmaxf(p0.y + p1.y + p2.y + bb.y, 0.f);
  r.z = fmaxf(p0.z + p1.z + p2.z + bb.z, 0.f);
  r.w = fmaxf(p0.w + p1.w + p2.w + bb.w, 0.f);
  *(float4*)(x2 + (size_t)i4 * 4) = r;
}

// --------------------------- 1x1 heads GEMM --------------------------------
// logits[m][0..63] = x2[m][:] @ Wco + bco   (grid 40)
__global__ __launch_bounds__(256) void gemm1x1(const float* __restrict__ x2,
                                               const float* __restrict__ Wco,
                                               const float* __restrict__ bco,
                                               float* __restrict__ logits) {
  __shared__ __align__(16) float At[32][68];
  __shared__ __align__(16) float Bt[32][64];
  int tid = threadIdx.x;
  int m0 = blockIdx.x << 6;
  int ti = tid >> 4, tj = tid & 15;
  int si = tid >> 2, sq = tid & 3;
  int skk = tid >> 3, sr = tid & 7;
  float acc[4][4] = {{0.f}};
  int m = m0 + si;
  bool mv = m < NM;
  const float* arow = x2 + (((size_t)(mv ? m : 0)) << 9);
  for (int c0 = 0; c0 < CIN; c0 += 32) {
    __syncthreads();
    float4 a0 = make_float4(0.f, 0.f, 0.f, 0.f), a1 = a0;
    if (mv) {
      a0 = *(const float4*)(arow + c0 + (sq << 2));
      a1 = *(const float4*)(arow + c0 + 16 + (sq << 2));
    }
    int kb = sq << 2;
    At[kb + 0][si] = a0.x; At[kb + 1][si] = a0.y; At[kb + 2][si] = a0.z; At[kb + 3][si] = a0.w;
    At[kb + 16][si] = a1.x; At[kb + 17][si] = a1.y; At[kb + 18][si] = a1.z; At[kb + 19][si] = a1.w;
    const float* bp = Wco + (size_t)(c0 + skk) * 64;
    *(float4*)&Bt[skk][sr << 2] = *(const float4*)(bp + (sr << 2));
    *(float4*)&Bt[skk][32 + (sr << 2)] = *(const float4*)(bp + 32 + (sr << 2));
    __syncthreads();
#pragma unroll
    for (int kk = 0; kk < 32; kk++) {
      float4 avv = *(const float4*)&At[kk][ti << 2];
      float4 bvv = *(const float4*)&Bt[kk][tj << 2];
      float a_[4] = {avv.x, avv.y, avv.z, avv.w};
      float b_[4] = {bvv.x, bvv.y, bvv.z, bvv.w};
#pragma unroll
      for (int u = 0; u < 4; u++)
#pragma unroll
        for (int v = 0; v < 4; v++) acc[u][v] += a_[u] * b_[v];
    }
  }
  float4 bias = *(const float4*)(bco + (tj << 2));
#pragma unroll
  for (int u = 0; u < 4; u++) {
    int mr = m0 + (ti << 2) + u;
    if (mr < NM) {
      float4 r = make_float4(acc[u][0] + bias.x, acc[u][1] + bias.y, acc[u][2] + bias.z,
                             acc[u][3] + bias.w);
      *(float4*)(logits + (size_t)mr * 64 + (tj << 2)) = r;
    }
  }
}

// --------------------------- scores + proposals ----------------------------
__global__ __launch_bounds__(256) void score_box_kernel(const float* __restrict__ logits,
                                                        const int* __restrict__ ih,
                                                        const int* __restrict__ iw,
                                                        BaseAnchors ba,
                                                        float* __restrict__ scores,
                                                        float* __restrict__ props) {
#pragma clang fp contract(off)
  int n = blockIdx.x * 256 + threadIdx.x;
  if (n >= NBATCH * NANCH) return;
  int b = n / NANCH;
  int r = n % NANCH;
  int pos = r / 9, aa = r % 9;
  int py = pos / HWDIM, px = pos % HWDIM;
  const float* L = logits + (size_t)(b * NPOS + pos) * 64;
  float l0 = L[2 * aa], l1 = L[2 * aa + 1];
  float mx = fmaxf(l0, l1);
  float e0 = expf(l0 - mx), e1 = expf(l1 - mx);
  float s = e1 / (e0 + e1);
  float d0 = L[18 + 4 * aa + 0], d1 = L[18 + 4 * aa + 1];
  float d2 = L[18 + 4 * aa + 2], d3 = L[18 + 4 * aa + 3];
  float xf = (float)px * 32.f, yf = (float)py * 32.f;
  float ax1 = ba.x1[aa] + xf, ay1 = ba.y1[aa] + yf;
  float ax2 = ba.x2[aa] + xf, ay2 = ba.y2[aa] + yf;
  float wA = ax2 - ax1, hA = ay2 - ay1;
  float cx = ax1 + 0.5f * wA, cy = ay1 + 0.5f * hA;
  float pcx = d0 * wA + cx, pcy = d1 * hA + cy;
  float pw = expf(d2) * wA, ph = expf(d3) * hA;
  float x1 = pcx - 0.5f * pw, y1 = pcy - 0.5f * ph;
  float x2 = pcx + 0.5f * pw, y2 = pcy + 0.5f * ph;
  float W = (float)iw[0], H = (float)ih[0];
  x1 = fminf(fmaxf(x1, 0.f), W);
  y1 = fminf(fmaxf(y1, 0.f), H);
  x2 = fminf(fmaxf(x2, 0.f), W);
  y2 = fminf(fmaxf(y2, 0.f), H);
  scores[n] = s;
  *(float4*)(props + (size_t)n * 4) = make_float4(x1, y1, x2, y2);
}

// --------------------------- sort (bitonic, stable ties) -------------------
__global__ __launch_bounds__(1024) void sort_kernel(const float* __restrict__ scores,
                                                    const float* __restrict__ props,
                                                    int* __restrict__ order,
                                                    float* __restrict__ sb) {
  __shared__ unsigned long long keys[8192];
  int b = blockIdx.x, tid = threadIdx.x;
  const float* sc = scores + (size_t)b * NANCH;
  for (int i = tid; i < 8192; i += 1024) {
    unsigned long long k = 0ull;
    if (i < NANCH) {
      unsigned int sbits = __float_as_uint(sc[i]);  // scores > 0 -> order-preserving bits
      k = (((unsigned long long)sbits) << 32) | (unsigned long long)(~(unsigned int)i);
    }
    keys[i] = k;
  }
  __syncthreads();
  for (int k = 2; k <= 8192; k <<= 1) {
    for (int j = k >> 1; j > 0; j >>= 1) {
#pragma unroll
      for (int s = 0; s < 8; s++) {
        int i = tid + (s << 10);
        int p = i ^ j;
        if (p > i) {
          unsigned long long a = keys[i], c = keys[p];
          bool up = ((i & k) == 0);
          bool sw = up ? (a < c) : (a > c);  // descending overall
          if (sw) { keys[i] = c; keys[p] = a; }
        }
      }
      __syncthreads();
    }
  }
  for (int i = tid; i < NANCH; i += 1024) {
    unsigned long long kk = keys[i];
    int orig = (int)(~(unsigned int)kk);
    order[b * NANCH + i] = orig;
    float4 p = *(const float4*)(props + ((size_t)b * NANCH + orig) * 4);
    *(float4*)(sb + ((size_t)b * NANCH + i) * 4) = p;
  }
}

// --------------------------- NMS bitmask -----------------------------------
__global__ __launch_bounds__(64) void nms_mask_kernel(const float* __restrict__ sb,
                                                      unsigned long long* __restrict__ mask) {
#pragma clang fp contract(off)
  int rb = blockIdx.x, cb = blockIdx.y, b = blockIdx.z;
  if (cb < rb) return;
  int lane = threadIdx.x;
  __shared__ float4 cbox[64];
  int j0 = cb << 6;
  const float* sbb = sb + (size_t)b * NANCH * 4;
  if (j0 + lane < NANCH) cbox[lane] = *(const float4*)(sbb + (size_t)(j0 + lane) * 4);
  __syncthreads();
  int i = (rb << 6) + lane;
  if (i >= NANCH) return;
  float4 rbox = *(const float4*)(sbb + (size_t)i * 4);
  float rarea = (rbox.z - rbox.x) * (rbox.w - rbox.y);
  unsigned long long bits = 0ull;
  int jmax = NANCH - j0;
  if (jmax > 64) jmax = 64;
  for (int l = 0; l < jmax; l++) {
    int j = j0 + l;
    if (j > i) {
      float4 c = cbox[l];
      float carea = (c.z - c.x) * (c.w - c.y);
      float ltx = fmaxf(rbox.x, c.x), lty = fmaxf(rbox.y, c.y);
      float rbx = fminf(rbox.z, c.z), rby = fminf(rbox.w, c.w);
      float wx = fmaxf(rbx - ltx, 0.f);
      float wy = fmaxf(rby - lty, 0.f);
      float inter = wx * wy;
      float iou = inter / (rarea + carea - inter);  // 0/0 -> NaN -> compare false
      if (iou > 0.7f) bits |= (1ull << l);
    }
  }
  mask[((size_t)b * NANCH + i) * NW + cb] = bits;
}

// --------------------------- NMS serial scan + output ----------------------
// One wave per batch. Lane l owns remv words l and l+64 (if < NW).
// Per 64-row stripe: (A) register serial chain via readlane over the diagonal
// word to find alive rows; (B) OR alive rows' mask words (>= diagonal only;
// below-diagonal words are never written) into remv, 8 rows per chunk so the
// temporaries stay in registers (R1 version used v[64] arrays -> scratch).
__global__ __launch_bounds__(64, 1) void nms_scan_kernel(const unsigned long long* __restrict__ mask,
                                                         const int* __restrict__ order,
                                                         const float* __restrict__ sb,
                                                         float* __restrict__ out) {
  int b = blockIdx.x;
  int lane = threadIdx.x;
  const unsigned long long* mb = mask + (size_t)b * NANCH * NW;
  unsigned long long remv0 = 0ull, remv1 = 0ull;  // words lane, lane+64
  __shared__ unsigned long long sup_lds[NW];
  int w1 = lane + 64;
  bool has2 = (w1 < NW);

  for (int s = 0; s < NW; s++) {
    int r0 = s << 6;
    int nrows = NANCH - r0;
    if (nrows > 64) nrows = 64;
    // Phase A: diagonal word for this stripe (row r0+lane, word s)
    unsigned long long Mw = (lane < nrows) ? mb[(size_t)(r0 + lane) * NW + s] : 0ull;
    unsigned long long cur = (s < 64) ? bcast64(remv0, s) : bcast64(remv1, s - 64);
    if (nrows < 64) cur |= (~0ull) << nrows;  // phantom rows = suppressed
    unsigned long long alive = 0ull;
#pragma unroll
    for (int t = 0; t < 64; t++) {
      if (!((cur >> t) & 1ull)) {
        alive |= (1ull << t);
        cur |= bcast64(Mw, t);
      }
    }
    // Phase B: OR alive rows' mask words into remv (words >= s only)
    bool g0 = (lane >= s);
    bool g1 = has2 && (w1 >= s);
    for (int t0 = 0; t0 < 64; t0 += 8) {
      unsigned int ca = (unsigned int)((alive >> t0) & 0xffull);
      if (!ca) continue;  // wave-uniform skip
      unsigned long long va[8], vb[8];
#pragma unroll
      for (int q = 0; q < 8; q++) {
        const unsigned long long* rp = mb + (size_t)(r0 + t0 + q) * NW;
        bool rowv = ((ca >> q) & 1u) != 0u;
        va[q] = (rowv && g0) ? rp[lane] : 0ull;
        vb[q] = (rowv && g1) ? rp[w1] : 0ull;
      }
#pragma unroll
      for (int q = 0; q < 8; q++) { remv0 |= va[q]; remv1 |= vb[q]; }
    }
  }
  sup_lds[lane] = remv0;
  if (has2) sup_lds[w1] = remv1;
  __syncthreads();
  // write output: out[b][orig] = kept ? sorted_box : 0
  for (int i = lane; i < NANCH; i += 64) {
    unsigned long long s = sup_lds[i >> 6];
    bool kept = !((s >> (i & 63)) & 1ull);
    int orig = order[b * NANCH + i];
    float4 p = *(const float4*)(sb + ((size_t)b * NANCH + i) * 4);
    float4 o = kept ? p : make_float4(0.f, 0.f, 0.f, 0.f);
    *(float4*)(out + ((size_t)b * NANCH + orig) * 4) = o;
  }
}

// --------------------------- host launcher ---------------------------------

extern "C" void kernel_launch(void* const* d_in, const int* in_sizes, int n_in,
                              void* d_out, int out_size, void* d_ws, size_t ws_size,
                              hipStream_t stream) {
  const float* features = (const float*)d_in[0];
  const float* conv_w   = (const float*)d_in[1];
  const float* conv_b   = (const float*)d_in[2];
  const float* cls_w    = (const float*)d_in[3];
  const float* cls_b    = (const float*)d_in[4];
  const float* bbox_w   = (const float*)d_in[5];
  const float* bbox_b   = (const float*)d_in[6];
  const int*   img_h    = (const int*)d_in[7];
  const int*   img_w    = (const int*)d_in[8];
  float* out = (float*)d_out;
  char* ws = (char*)d_ws;

  // workspace layout (bytes); MASK aliases FM/WT/XP which are dead by then
  const size_t OFF_FM  = 0;                    // 5,120,000
  const size_t OFF_WT  = 5120000;              // 9,437,184
  const size_t OFF_XP  = 14557184;             // 15,360,000
  const size_t OFF_MASK = 0;                   // 15,840,000 (aliases FM..XP)
  const size_t OFF_X2  = 29917184;             // 5,120,000
  const size_t OFF_WCO = 35037184;             // 131,072
  const size_t OFF_BCO = 35168256;             // 256
  const size_t OFF_LOG = 35168512;             // 640,000
  const size_t OFF_SC  = 35808512;             // 90,000
  const size_t OFF_PR  = 35898512;             // 360,000
  const size_t OFF_ORD = 36258512;             // 90,000
  const size_t OFF_SB  = 36348512;             // 360,000
  const size_t WS_NEEDED = 36708512;
  if (ws_size < WS_NEEDED) return;

  float* fm   = (float*)(ws + OFF_FM);
  float* Wt   = (float*)(ws + OFF_WT);
  float* xp   = (float*)(ws + OFF_XP);
  unsigned long long* mask = (unsigned long long*)(ws + OFF_MASK);
  float* x2   = (float*)(ws + OFF_X2);
  float* Wco  = (float*)(ws + OFF_WCO);
  float* bco  = (float*)(ws + OFF_BCO);
  float* logits = (float*)(ws + OFF_LOG);
  float* scores = (float*)(ws + OFF_SC);
  float* props  = (float*)(ws + OFF_PR);
  int*   order  = (int*)(ws + OFF_ORD);
  float* sb     = (float*)(ws + OFF_SB);

  // base anchors in double, rounded to f32 exactly like numpy
  BaseAnchors ba;
  {
    const double scales[3] = {64.0, 128.0, 256.0};
    const double ratios[3] = {0.5, 1.0, 2.0};
    int a = 0;
    for (int si = 0; si < 3; si++)
      for (int ri = 0; ri < 3; ri++, a++) {
        double w = scales[si] * sqrt(ratios[ri]);
        double h = scales[si] / sqrt(ratios[ri]);
        ba.x1[a] = (float)(-w / 2.0);
        ba.y1[a] = (float)(-h / 2.0);
        ba.x2[a] = (float)(w / 2.0);
        ba.y2[a] = (float)(h / 2.0);
      }
  }

  transpose_features<<<dim3(20, 16, 4), dim3(32, 8), 0, stream>>>(features, fm);
  transpose_weights<<<dim3(16, 16), 256, 0, stream>>>(conv_w, Wt);
  build_wco<<<128, 256, 0, stream>>>(cls_w, cls_b, bbox_w, bbox_b, Wco, bco);
  conv_gemm<<<dim3(40, 8, 3), 256, 0, stream>>>(fm, Wt, xp);
  combine_relu<<<1250, 256, 0, stream>>>(xp, conv_b, x2);
  gemm1x1<<<40, 256, 0, stream>>>(x2, Wco, bco, logits);
  score_box_kernel<<<88, 256, 0, stream>>>(logits, img_h, img_w, ba, scores, props);
  sort_kernel<<<4, 1024, 0, stream>>>(scores, props, order, sb);
  nms_mask_kernel<<<dim3(NW, NW, 4), 64, 0, stream>>>(sb, mask);
  nms_scan_kernel<<<4, 64, 0, stream>>>(mask, order, sb, out);
}

// Round 3
// 904.396 us; speedup vs baseline: 1.1220x; 1.1220x over previous
//
#include <hip/hip_runtime.h>

// ---------------------------------------------------------------------------
// RPN forward: conv3x3(512->512)+relu, 1x1 heads (18 cls, 36 bbox),
// anchor decode + clip, softmax score, greedy NMS (0.7), keep-masked boxes.
// All decision math in fp32 with contraction OFF to track the numpy reference.
// R3: mask stored TRANSPOSED (maskT[b][word][row]) -> coalesced writes and
//     dense coalesced scan reads; scan evaluates only column s at stripe s
//     (lazy), with ctz-driven serial chain over alive rows only.
//     (R1: v[64] arrays spilled to scratch, 517us. R2: compiler sank chunked
//      loads into serial load->or chain, 655us.)
// ---------------------------------------------------------------------------

#define NBATCH 4
#define HWDIM  25
#define NPOS   625            // 25*25
#define NM     2500           // NBATCH*NPOS
#define CIN    512
#define NANCH  5625           // NPOS*9
#define NW     88             // ceil(NANCH/64)

typedef unsigned long long u64;

struct BaseAnchors { float x1[9], y1[9], x2[9], y2[9]; };

__device__ __forceinline__ u64 bcast64(u64 v, int lane) {
  unsigned int lo = (unsigned int)v;
  unsigned int hi = (unsigned int)(v >> 32);
  lo = (unsigned int)__builtin_amdgcn_readlane((int)lo, lane);
  hi = (unsigned int)__builtin_amdgcn_readlane((int)hi, lane);
  return (((u64)hi) << 32) | (u64)lo;
}

// --------------------------- prep: transposes ------------------------------

// f[b][c][pos] -> fm[b*625+pos][c]
__global__ void transpose_features(const float* __restrict__ f, float* __restrict__ fm) {
  __shared__ float tile[32][33];
  int b  = blockIdx.z;
  int p0 = blockIdx.x * 32;
  int c0 = blockIdx.y * 32;
  int tx = threadIdx.x, ty = threadIdx.y;  // (32, 8)
#pragma unroll
  for (int j = 0; j < 4; j++) {
    int c = c0 + ty + j * 8;
    int p = p0 + tx;
    if (p < NPOS) tile[ty + j * 8][tx] = f[((size_t)(b * CIN + c)) * NPOS + p];
  }
  __syncthreads();
#pragma unroll
  for (int j = 0; j < 4; j++) {
    int p = p0 + ty + j * 8;
    int c = c0 + tx;
    if (p < NPOS) fm[((size_t)(b * NPOS + p)) * CIN + c] = tile[tx][ty + j * 8];
  }
}

// conv_w[o][c][tap] -> Wt[tap][c][o]
__global__ __launch_bounds__(256) void transpose_weights(const float* __restrict__ cw,
                                                         float* __restrict__ Wt) {
  __shared__ float tile[32][289];
  int o0 = blockIdx.x * 32, c0 = blockIdx.y * 32;
  int tid = threadIdx.x;
#pragma unroll
  for (int j = 0; j < 36; j++) {
    int idx = tid + j * 256;            // 0..9215
    int o = idx / 288, kk = idx % 288;  // kk = c_rel*9 + tap
    tile[o][kk] = cw[((size_t)(o0 + o)) * 4608 + c0 * 9 + kk];
  }
  __syncthreads();
  int ol = tid & 31, pg = tid >> 5;  // 0..7
#pragma unroll
  for (int j = 0; j < 36; j++) {
    int pair = pg + j * 8;  // 0..287 == c_rel*9 + tap
    int c = pair / 9, tap = pair % 9;
    Wt[((size_t)tap * CIN + (c0 + c)) * 512 + o0 + ol] = tile[ol][pair];
  }
}

// combined 1x1 head weights: Wco[c][o] (o: 0..17 cls, 18..53 bbox, 54..63 zero)
__global__ void build_wco(const float* __restrict__ clsw, const float* __restrict__ clsb,
                          const float* __restrict__ bw, const float* __restrict__ bbb,
                          float* __restrict__ Wco, float* __restrict__ bco) {
  int idx = blockIdx.x * 256 + threadIdx.x;
  if (idx < 512 * 64) {
    int c = idx >> 6, o = idx & 63;
    float v = 0.f;
    if (o < 18) v = clsw[o * 512 + c];
    else if (o < 54) v = bw[(o - 18) * 512 + c];
    Wco[idx] = v;
  }
  if (idx < 64) {
    float v = 0.f;
    if (idx < 18) v = clsb[idx];
    else if (idx < 54) v = bbb[idx - 18];
    bco[idx] = v;
  }
}

// --------------------------- conv3x3 implicit GEMM -------------------------
// grid (40, 8, 3): 64 m-rows x 64 o-cols per block, part = 3 taps (dy fixed).
// Writes partial sums (no bias/relu) to xp[part][m][o].
__global__ __launch_bounds__(256) void conv_gemm(const float* __restrict__ fm,
                                                 const float* __restrict__ Wt,
                                                 float* __restrict__ xp) {
  __shared__ __align__(16) float At[32][68];
  __shared__ __align__(16) float Bt[32][64];
  int tid = threadIdx.x;
  int m0 = blockIdx.x << 6;
  int o0 = blockIdx.y << 6;
  int part = blockIdx.z;  // 0..2 -> dy = part-1
  int ti = tid >> 4, tj = tid & 15;   // compute tile 4x4
  int si = tid >> 2, sq = tid & 3;    // A staging: row si, col quad sq
  int skk = tid >> 3, sr = tid & 7;   // B staging: k-row skk, col oct sr
  float acc[4][4] = {{0.f}};

  int m = m0 + si;
  bool mv = m < NM;
  int mm = mv ? m : 0;
  int bb = mm / NPOS, rem = mm % NPOS;
  int hh = rem / HWDIM, ww = rem % HWDIM;
  int dy = part - 1;

  for (int tt = 0; tt < 3; tt++) {
    int tap = part * 3 + tt;
    int dx = tt - 1;
    int h2 = hh + dy, w2 = ww + dx;
    bool av = mv && ((unsigned)h2 < (unsigned)HWDIM) && ((unsigned)w2 < (unsigned)HWDIM);
    const float* arow = fm + (((size_t)(bb * NPOS + h2 * HWDIM + w2)) << 9);
    const float* bbase = Wt + (((size_t)tap) << 18) + o0;
    for (int c0 = 0; c0 < CIN; c0 += 32) {
      __syncthreads();
      float4 a0 = make_float4(0.f, 0.f, 0.f, 0.f), a1 = a0;
      if (av) {
        a0 = *(const float4*)(arow + c0 + (sq << 2));
        a1 = *(const float4*)(arow + c0 + 16 + (sq << 2));
      }
      int kb = sq << 2;
      At[kb + 0][si] = a0.x; At[kb + 1][si] = a0.y; At[kb + 2][si] = a0.z; At[kb + 3][si] = a0.w;
      At[kb + 16][si] = a1.x; At[kb + 17][si] = a1.y; At[kb + 18][si] = a1.z; At[kb + 19][si] = a1.w;
      const float* bp = bbase + (((size_t)(c0 + skk)) << 9);
      *(float4*)&Bt[skk][sr << 2] = *(const float4*)(bp + (sr << 2));
      *(float4*)&Bt[skk][32 + (sr << 2)] = *(const float4*)(bp + 32 + (sr << 2));
      __syncthreads();
#pragma unroll
      for (int kk = 0; kk < 32; kk++) {
        float4 avv = *(const float4*)&At[kk][ti << 2];
        float4 bvv = *(const float4*)&Bt[kk][tj << 2];
        float a_[4] = {avv.x, avv.y, avv.z, avv.w};
        float b_[4] = {bvv.x, bvv.y, bvv.z, bvv.w};
#pragma unroll
        for (int u = 0; u < 4; u++)
#pragma unroll
          for (int v = 0; v < 4; v++) acc[u][v] += a_[u] * b_[v];
      }
    }
  }
  float* outp = xp + (size_t)part * (NM * 512);
#pragma unroll
  for (int u = 0; u < 4; u++) {
    int mr = m0 + (ti << 2) + u;
    if (mr < NM) {
      float4 r = make_float4(acc[u][0], acc[u][1], acc[u][2], acc[u][3]);
      *(float4*)(outp + (((size_t)mr) << 9) + o0 + (tj << 2)) = r;
    }
  }
}

// x2 = relu(xp0+xp1+xp2+bias)
__global__ void combine_relu(const float* __restrict__ xp, const float* __restrict__ bias,
                             float* __restrict__ x2) {
  int i4 = blockIdx.x * 256 + threadIdx.x;  // over 320000 float4s
  if (i4 >= NM * 128) return;
  float4 p0 = *(const float4*)(xp + (size_t)i4 * 4);
  float4 p1 = *(const float4*)(xp + (size_t)(NM * 512) + (size_t)i4 * 4);
  float4 p2 = *(const float4*)(xp + (size_t)(2 * NM * 512) + (size_t)i4 * 4);
  float4 bb = *(const float4*)(bias + (i4 & 127) * 4);
  float4 r;
  r.x = fmaxf(p0.x + p1.x + p2.x + bb.x, 0.f);
  r.y = fmaxf(p0.y + p1.y + p2.y + bb.y, 0.f);
  r.z = fmaxf(p0.z + p1.z + p2.z + bb.z, 0.f);
  r.w = fmaxf(p0.w + p1.w + p2.w + bb.w, 0.f);
  *(float4*)(x2 + (size_t)i4 * 4) = r;
}

// --------------------------- 1x1 heads GEMM --------------------------------
// logits[m][0..63] = x2[m][:] @ Wco + bco   (grid 40)
__global__ __launch_bounds__(256) void gemm1x1(const float* __restrict__ x2,
                                               const float* __restrict__ Wco,
                                               const float* __restrict__ bco,
                                               float* __restrict__ logits) {
  __shared__ __align__(16) float At[32][68];
  __shared__ __align__(16) float Bt[32][64];
  int tid = threadIdx.x;
  int m0 = blockIdx.x << 6;
  int ti = tid >> 4, tj = tid & 15;
  int si = tid >> 2, sq = tid & 3;
  int skk = tid >> 3, sr = tid & 7;
  float acc[4][4] = {{0.f}};
  int m = m0 + si;
  bool mv = m < NM;
  const float* arow = x2 + (((size_t)(mv ? m : 0)) << 9);
  for (int c0 = 0; c0 < CIN; c0 += 32) {
    __syncthreads();
    float4 a0 = make_float4(0.f, 0.f, 0.f, 0.f), a1 = a0;
    if (mv) {
      a0 = *(const float4*)(arow + c0 + (sq << 2));
      a1 = *(const float4*)(arow + c0 + 16 + (sq << 2));
    }
    int kb = sq << 2;
    At[kb + 0][si] = a0.x; At[kb + 1][si] = a0.y; At[kb + 2][si] = a0.z; At[kb + 3][si] = a0.w;
    At[kb + 16][si] = a1.x; At[kb + 17][si] = a1.y; At[kb + 18][si] = a1.z; At[kb + 19][si] = a1.w;
    const float* bp = Wco + (size_t)(c0 + skk) * 64;
    *(float4*)&Bt[skk][sr << 2] = *(const float4*)(bp + (sr << 2));
    *(float4*)&Bt[skk][32 + (sr << 2)] = *(const float4*)(bp + 32 + (sr << 2));
    __syncthreads();
#pragma unroll
    for (int kk = 0; kk < 32; kk++) {
      float4 avv = *(const float4*)&At[kk][ti << 2];
      float4 bvv = *(const float4*)&Bt[kk][tj << 2];
      float a_[4] = {avv.x, avv.y, avv.z, avv.w};
      float b_[4] = {bvv.x, bvv.y, bvv.z, bvv.w};
#pragma unroll
      for (int u = 0; u < 4; u++)
#pragma unroll
        for (int v = 0; v < 4; v++) acc[u][v] += a_[u] * b_[v];
    }
  }
  float4 bias = *(const float4*)(bco + (tj << 2));
#pragma unroll
  for (int u = 0; u < 4; u++) {
    int mr = m0 + (ti << 2) + u;
    if (mr < NM) {
      float4 r = make_float4(acc[u][0] + bias.x, acc[u][1] + bias.y, acc[u][2] + bias.z,
                             acc[u][3] + bias.w);
      *(float4*)(logits + (size_t)mr * 64 + (tj << 2)) = r;
    }
  }
}

// --------------------------- scores + proposals ----------------------------
__global__ __launch_bounds__(256) void score_box_kernel(const float* __restrict__ logits,
                                                        const int* __restrict__ ih,
                                                        const int* __restrict__ iw,
                                                        BaseAnchors ba,
                                                        float* __restrict__ scores,
                                                        float* __restrict__ props) {
#pragma clang fp contract(off)
  int n = blockIdx.x * 256 + threadIdx.x;
  if (n >= NBATCH * NANCH) return;
  int b = n / NANCH;
  int r = n % NANCH;
  int pos = r / 9, aa = r % 9;
  int py = pos / HWDIM, px = pos % HWDIM;
  const float* L = logits + (size_t)(b * NPOS + pos) * 64;
  float l0 = L[2 * aa], l1 = L[2 * aa + 1];
  float mx = fmaxf(l0, l1);
  float e0 = expf(l0 - mx), e1 = expf(l1 - mx);
  float s = e1 / (e0 + e1);
  float d0 = L[18 + 4 * aa + 0], d1 = L[18 + 4 * aa + 1];
  float d2 = L[18 + 4 * aa + 2], d3 = L[18 + 4 * aa + 3];
  float xf = (float)px * 32.f, yf = (float)py * 32.f;
  float ax1 = ba.x1[aa] + xf, ay1 = ba.y1[aa] + yf;
  float ax2 = ba.x2[aa] + xf, ay2 = ba.y2[aa] + yf;
  float wA = ax2 - ax1, hA = ay2 - ay1;
  float cx = ax1 + 0.5f * wA, cy = ay1 + 0.5f * hA;
  float pcx = d0 * wA + cx, pcy = d1 * hA + cy;
  float pw = expf(d2) * wA, ph = expf(d3) * hA;
  float x1 = pcx - 0.5f * pw, y1 = pcy - 0.5f * ph;
  float x2 = pcx + 0.5f * pw, y2 = pcy + 0.5f * ph;
  float W = (float)iw[0], H = (float)ih[0];
  x1 = fminf(fmaxf(x1, 0.f), W);
  y1 = fminf(fmaxf(y1, 0.f), H);
  x2 = fminf(fmaxf(x2, 0.f), W);
  y2 = fminf(fmaxf(y2, 0.f), H);
  scores[n] = s;
  *(float4*)(props + (size_t)n * 4) = make_float4(x1, y1, x2, y2);
}

// --------------------------- sort (bitonic, stable ties) -------------------
__global__ __launch_bounds__(1024) void sort_kernel(const float* __restrict__ scores,
                                                    const float* __restrict__ props,
                                                    int* __restrict__ order,
                                                    float* __restrict__ sb) {
  __shared__ u64 keys[8192];
  int b = blockIdx.x, tid = threadIdx.x;
  const float* sc = scores + (size_t)b * NANCH;
  for (int i = tid; i < 8192; i += 1024) {
    u64 k = 0ull;
    if (i < NANCH) {
      unsigned int sbits = __float_as_uint(sc[i]);  // scores > 0 -> order-preserving bits
      k = (((u64)sbits) << 32) | (u64)(~(unsigned int)i);
    }
    keys[i] = k;
  }
  __syncthreads();
  for (int k = 2; k <= 8192; k <<= 1) {
    for (int j = k >> 1; j > 0; j >>= 1) {
#pragma unroll
      for (int s = 0; s < 8; s++) {
        int i = tid + (s << 10);
        int p = i ^ j;
        if (p > i) {
          u64 a = keys[i], c = keys[p];
          bool up = ((i & k) == 0);
          bool sw = up ? (a < c) : (a > c);  // descending overall
          if (sw) { keys[i] = c; keys[p] = a; }
        }
      }
      __syncthreads();
    }
  }
  for (int i = tid; i < NANCH; i += 1024) {
    u64 kk = keys[i];
    int orig = (int)(~(unsigned int)kk);
    order[b * NANCH + i] = orig;
    float4 p = *(const float4*)(props + ((size_t)b * NANCH + orig) * 4);
    *(float4*)(sb + ((size_t)b * NANCH + i) * 4) = p;
  }
}

// --------------------------- NMS bitmask (transposed) ----------------------
// maskT[b][word cb][row i] : bit l of word = suppression of col j=cb*64+l by
// row i (j > i). Lane-consecutive rows -> fully coalesced 8B-stride stores.
__global__ __launch_bounds__(64) void nms_mask_kernel(const float* __restrict__ sb,
                                                      u64* __restrict__ maskT) {
#pragma clang fp contract(off)
  int rb = blockIdx.x, cb = blockIdx.y, b = blockIdx.z;
  if (cb < rb) return;
  int lane = threadIdx.x;
  __shared__ float4 cbox[64];
  int j0 = cb << 6;
  const float* sbb = sb + (size_t)b * NANCH * 4;
  if (j0 + lane < NANCH) cbox[lane] = *(const float4*)(sbb + (size_t)(j0 + lane) * 4);
  __syncthreads();
  int i = (rb << 6) + lane;
  if (i >= NANCH) return;
  float4 rbox = *(const float4*)(sbb + (size_t)i * 4);
  float rarea = (rbox.z - rbox.x) * (rbox.w - rbox.y);
  u64 bits = 0ull;
  int jmax = NANCH - j0;
  if (jmax > 64) jmax = 64;
  for (int l = 0; l < jmax; l++) {
    int j = j0 + l;
    if (j > i) {
      float4 c = cbox[l];
      float carea = (c.z - c.x) * (c.w - c.y);
      float ltx = fmaxf(rbox.x, c.x), lty = fmaxf(rbox.y, c.y);
      float rbx = fminf(rbox.z, c.z), rby = fminf(rbox.w, c.w);
      float wx = fmaxf(rbx - ltx, 0.f);
      float wy = fmaxf(rby - lty, 0.f);
      float inter = wx * wy;
      float iou = inter / (rarea + carea - inter);  // 0/0 -> NaN -> compare false
      if (iou > 0.7f) bits |= (1ull << l);
    }
  }
  maskT[((size_t)b * NW + cb) * NANCH + i] = bits;
}

// --------------------------- NMS lazy serial scan + output -----------------
// One wave per batch. Greedy NMS over sorted order. At stripe s (rows
// r0=64s..r0+63) the only suppression word needed is word s:
//   cur = OR over alive rows r<r0 of maskT[s][r]   (dense coalesced loads,
//         masked per-row by the keep bit, 8-unrolled for MLP, shfl-OR reduce)
// then a ctz-driven serial chain over the stripe's diagonal word decides
// alive rows within the stripe (iterates alive rows only).
__global__ __launch_bounds__(64, 1) void nms_scan_kernel(const u64* __restrict__ maskT,
                                                         const int* __restrict__ order,
                                                         const float* __restrict__ sb,
                                                         float* __restrict__ out) {
  int b = blockIdx.x;
  int lane = threadIdx.x;
  const u64* mb = maskT + (size_t)b * NW * NANCH;
  u64 keep0 = 0ull, keep1 = 0ull;  // keep words lane, lane+64
  u64 lanebit = 1ull << lane;
  __shared__ u64 keep_lds[NW];

  for (int s = 0; s < NW; s++) {
    const u64* col = mb + (size_t)s * NANCH;
    int r0 = s << 6;
    int nrows = NANCH - r0;
    if (nrows > 64) nrows = 64;

    // ---- cur = OR over earlier alive rows of col[r] ----
    u64 acc = 0ull;
    int c = 0;
    for (; c + 8 <= s; c += 8) {
      u64 v0 = col[((c + 0) << 6) + lane];
      u64 v1 = col[((c + 1) << 6) + lane];
      u64 v2 = col[((c + 2) << 6) + lane];
      u64 v3 = col[((c + 3) << 6) + lane];
      u64 v4 = col[((c + 4) << 6) + lane];
      u64 v5 = col[((c + 5) << 6) + lane];
      u64 v6 = col[((c + 6) << 6) + lane];
      u64 v7 = col[((c + 7) << 6) + lane];
      u64 k0 = (c + 0 < 64) ? bcast64(keep0, c + 0) : bcast64(keep1, c + 0 - 64);
      u64 k1 = (c + 1 < 64) ? bcast64(keep0, c + 1) : bcast64(keep1, c + 1 - 64);
      u64 k2 = (c + 2 < 64) ? bcast64(keep0, c + 2) : bcast64(keep1, c + 2 - 64);
      u64 k3 = (c + 3 < 64) ? bcast64(keep0, c + 3) : bcast64(keep1, c + 3 - 64);
      u64 k4 = (c + 4 < 64) ? bcast64(keep0, c + 4) : bcast64(keep1, c + 4 - 64);
      u64 k5 = (c + 5 < 64) ? bcast64(keep0, c + 5) : bcast64(keep1, c + 5 - 64);
      u64 k6 = (c + 6 < 64) ? bcast64(keep0, c + 6) : bcast64(keep1, c + 6 - 64);
      u64 k7 = (c + 7 < 64) ? bcast64(keep0, c + 7) : bcast64(keep1, c + 7 - 64);
      acc |= ((k0 & lanebit) ? v0 : 0ull) | ((k1 & lanebit) ? v1 : 0ull) |
             ((k2 & lanebit) ? v2 : 0ull) | ((k3 & lanebit) ? v3 : 0ull) |
             ((k4 & lanebit) ? v4 : 0ull) | ((k5 & lanebit) ? v5 : 0ull) |
             ((k6 & lanebit) ? v6 : 0ull) | ((k7 & lanebit) ? v7 : 0ull);
    }
    for (; c < s; c++) {
      u64 v = col[(c << 6) + lane];
      u64 k = (c < 64) ? bcast64(keep0, c) : bcast64(keep1, c - 64);
      acc |= (k & lanebit) ? v : 0ull;
    }
    // cross-lane OR reduce (64-wide)
    unsigned int alo = (unsigned int)acc, ahi = (unsigned int)(acc >> 32);
#pragma unroll
    for (int off = 32; off > 0; off >>= 1) {
      alo |= (unsigned int)__shfl_xor((int)alo, off, 64);
      ahi |= (unsigned int)__shfl_xor((int)ahi, off, 64);
    }
    u64 cur = (((u64)ahi) << 32) | (u64)alo;

    // ---- serial chain within the stripe (alive rows only) ----
    u64 Mw = (lane < nrows) ? col[r0 + lane] : 0ull;
    u64 todo = ~cur;
    if (nrows < 64) todo &= ((1ull << nrows) - 1ull);
    u64 alive = 0ull;
    while (todo) {
      int t = (int)__builtin_ctzll(todo);
      alive |= (1ull << t);
      u64 sup = bcast64(Mw, t);
      todo &= ~(sup | (1ull << t));
    }
    if (s < 64) {
      if (lane == s) keep0 = alive;
    } else {
      if (lane == s - 64) keep1 = alive;
    }
  }

  keep_lds[lane] = keep0;
  if (lane + 64 < NW) keep_lds[lane + 64] = keep1;
  __syncthreads();
  // write output: out[b][orig] = kept ? sorted_box : 0
  for (int i = lane; i < NANCH; i += 64) {
    u64 kw = keep_lds[i >> 6];
    bool kept = ((kw >> (i & 63)) & 1ull) != 0ull;
    int orig = order[b * NANCH + i];
    float4 p = *(const float4*)(sb + ((size_t)b * NANCH + i) * 4);
    float4 o = kept ? p : make_float4(0.f, 0.f, 0.f, 0.f);
    *(float4*)(out + ((size_t)b * NANCH + orig) * 4) = o;
  }
}

// --------------------------- host launcher ---------------------------------

extern "C" void kernel_launch(void* const* d_in, const int* in_sizes, int n_in,
                              void* d_out, int out_size, void* d_ws, size_t ws_size,
                              hipStream_t stream) {
  const float* features = (const float*)d_in[0];
  const float* conv_w   = (const float*)d_in[1];
  const float* conv_b   = (const float*)d_in[2];
  const float* cls_w    = (const float*)d_in[3];
  const float* cls_b    = (const float*)d_in[4];
  const float* bbox_w   = (const float*)d_in[5];
  const float* bbox_b   = (const float*)d_in[6];
  const int*   img_h    = (const int*)d_in[7];
  const int*   img_w    = (const int*)d_in[8];
  float* out = (float*)d_out;
  char* ws = (char*)d_ws;

  // workspace layout (bytes); MASK aliases FM/WT/XP which are dead by then
  const size_t OFF_FM  = 0;                    // 5,120,000
  const size_t OFF_WT  = 5120000;              // 9,437,184
  const size_t OFF_XP  = 14557184;             // 15,360,000
  const size_t OFF_MASK = 0;                   // 15,840,000 (aliases FM..XP)
  const size_t OFF_X2  = 29917184;             // 5,120,000
  const size_t OFF_WCO = 35037184;             // 131,072
  const size_t OFF_BCO = 35168256;             // 256
  const size_t OFF_LOG = 35168512;             // 640,000
  const size_t OFF_SC  = 35808512;             // 90,000
  const size_t OFF_PR  = 35898512;             // 360,000
  const size_t OFF_ORD = 36258512;             // 90,000
  const size_t OFF_SB  = 36348512;             // 360,000
  const size_t WS_NEEDED = 36708512;
  if (ws_size < WS_NEEDED) return;

  float* fm   = (float*)(ws + OFF_FM);
  float* Wt   = (float*)(ws + OFF_WT);
  float* xp   = (float*)(ws + OFF_XP);
  u64*   maskT = (u64*)(ws + OFF_MASK);
  float* x2   = (float*)(ws + OFF_X2);
  float* Wco  = (float*)(ws + OFF_WCO);
  float* bco  = (float*)(ws + OFF_BCO);
  float* logits = (float*)(ws + OFF_LOG);
  float* scores = (float*)(ws + OFF_SC);
  float* props  = (float*)(ws + OFF_PR);
  int*   order  = (int*)(ws + OFF_ORD);
  float* sb     = (float*)(ws + OFF_SB);

  // base anchors in double, rounded to f32 exactly like numpy
  BaseAnchors ba;
  {
    const double scales[3] = {64.0, 128.0, 256.0};
    const double ratios[3] = {0.5, 1.0, 2.0};
    int a = 0;
    for (int si = 0; si < 3; si++)
      for (int ri = 0; ri < 3; ri++, a++) {
        double w = scales[si] * sqrt(ratios[ri]);
        double h = scales[si] / sqrt(ratios[ri]);
        ba.x1[a] = (float)(-w / 2.0);
        ba.y1[a] = (float)(-h / 2.0);
        ba.x2[a] = (float)(w / 2.0);
        ba.y2[a] = (float)(h / 2.0);
      }
  }

  transpose_features<<<dim3(20, 16, 4), dim3(32, 8), 0, stream>>>(features, fm);
  transpose_weights<<<dim3(16, 16), 256, 0, stream>>>(conv_w, Wt);
  build_wco<<<128, 256, 0, stream>>>(cls_w, cls_b, bbox_w, bbox_b, Wco, bco);
  conv_gemm<<<dim3(40, 8, 3), 256, 0, stream>>>(fm, Wt, xp);
  combine_relu<<<1250, 256, 0, stream>>>(xp, conv_b, x2);
  gemm1x1<<<40, 256, 0, stream>>>(x2, Wco, bco, logits);
  score_box_kernel<<<88, 256, 0, stream>>>(logits, img_h, img_w, ba, scores, props);
  sort_kernel<<<4, 1024, 0, stream>>>(scores, props, order, sb);
  nms_mask_kernel<<<dim3(NW, NW, 4), 64, 0, stream>>>(sb, maskT);
  nms_scan_kernel<<<4, 64, 0, stream>>>(maskT, order, sb, out);
}

// Round 4
// 804.816 us; speedup vs baseline: 1.2609x; 1.1237x over previous
//
#include <hip/hip_runtime.h>

// ---------------------------------------------------------------------------
// RPN forward: conv3x3(512->512)+relu, 1x1 heads (18 cls, 36 bbox),
// anchor decode + clip, softmax score, greedy NMS (0.7), keep-masked boxes.
// All decision math in fp32 with contraction OFF to track the numpy reference.
// R4 scan: incremental distributed remv (lane l owns words 2l,2l+1; O(kept)
//   coalesced row reads instead of O(NW^2) rescans) + inline-asm 8x
//   global_load_dwordx4 batches with in-block s_waitcnt to FORCE MLP
//   (R2/R3: compiler serialized every plain load at ~330cy each).
// ---------------------------------------------------------------------------

#define NBATCH 4
#define HWDIM  25
#define NPOS   625            // 25*25
#define NM     2500           // NBATCH*NPOS
#define CIN    512
#define NANCH  5625           // NPOS*9
#define NW     88             // ceil(NANCH/64)

typedef unsigned long long u64;
typedef unsigned int uint4v __attribute__((ext_vector_type(4)));

struct BaseAnchors { float x1[9], y1[9], x2[9], y2[9]; };

__device__ __forceinline__ u64 bcast64(u64 v, int lane) {
  unsigned int lo = (unsigned int)v;
  unsigned int hi = (unsigned int)(v >> 32);
  lo = (unsigned int)__builtin_amdgcn_readlane((int)lo, lane);
  hi = (unsigned int)__builtin_amdgcn_readlane((int)hi, lane);
  return (((u64)hi) << 32) | (u64)lo;
}

__device__ __forceinline__ u64 pk_lo(uint4v x) { return (((u64)x[1]) << 32) | (u64)x[0]; }
__device__ __forceinline__ u64 pk_hi(uint4v x) { return (((u64)x[3]) << 32) | (u64)x[2]; }

// --------------------------- prep: transposes ------------------------------

// f[b][c][pos] -> fm[b*625+pos][c]
__global__ void transpose_features(const float* __restrict__ f, float* __restrict__ fm) {
  __shared__ float tile[32][33];
  int b  = blockIdx.z;
  int p0 = blockIdx.x * 32;
  int c0 = blockIdx.y * 32;
  int tx = threadIdx.x, ty = threadIdx.y;  // (32, 8)
#pragma unroll
  for (int j = 0; j < 4; j++) {
    int c = c0 + ty + j * 8;
    int p = p0 + tx;
    if (p < NPOS) tile[ty + j * 8][tx] = f[((size_t)(b * CIN + c)) * NPOS + p];
  }
  __syncthreads();
#pragma unroll
  for (int j = 0; j < 4; j++) {
    int p = p0 + ty + j * 8;
    int c = c0 + tx;
    if (p < NPOS) fm[((size_t)(b * NPOS + p)) * CIN + c] = tile[tx][ty + j * 8];
  }
}

// conv_w[o][c][tap] -> Wt[tap][c][o]
__global__ __launch_bounds__(256) void transpose_weights(const float* __restrict__ cw,
                                                         float* __restrict__ Wt) {
  __shared__ float tile[32][289];
  int o0 = blockIdx.x * 32, c0 = blockIdx.y * 32;
  int tid = threadIdx.x;
#pragma unroll
  for (int j = 0; j < 36; j++) {
    int idx = tid + j * 256;            // 0..9215
    int o = idx / 288, kk = idx % 288;  // kk = c_rel*9 + tap
    tile[o][kk] = cw[((size_t)(o0 + o)) * 4608 + c0 * 9 + kk];
  }
  __syncthreads();
  int ol = tid & 31, pg = tid >> 5;  // 0..7
#pragma unroll
  for (int j = 0; j < 36; j++) {
    int pair = pg + j * 8;  // 0..287 == c_rel*9 + tap
    int c = pair / 9, tap = pair % 9;
    Wt[((size_t)tap * CIN + (c0 + c)) * 512 + o0 + ol] = tile[ol][pair];
  }
}

// combined 1x1 head weights: Wco[c][o] (o: 0..17 cls, 18..53 bbox, 54..63 zero)
__global__ void build_wco(const float* __restrict__ clsw, const float* __restrict__ clsb,
                          const float* __restrict__ bw, const float* __restrict__ bbb,
                          float* __restrict__ Wco, float* __restrict__ bco) {
  int idx = blockIdx.x * 256 + threadIdx.x;
  if (idx < 512 * 64) {
    int c = idx >> 6, o = idx & 63;
    float v = 0.f;
    if (o < 18) v = clsw[o * 512 + c];
    else if (o < 54) v = bw[(o - 18) * 512 + c];
    Wco[idx] = v;
  }
  if (idx < 64) {
    float v = 0.f;
    if (idx < 18) v = clsb[idx];
    else if (idx < 54) v = bbb[idx - 18];
    bco[idx] = v;
  }
}

// --------------------------- conv3x3 implicit GEMM -------------------------
// grid (40, 8, 3): 64 m-rows x 64 o-cols per block, part = 3 taps (dy fixed).
// Writes partial sums (no bias/relu) to xp[part][m][o].
__global__ __launch_bounds__(256) void conv_gemm(const float* __restrict__ fm,
                                                 const float* __restrict__ Wt,
                                                 float* __restrict__ xp) {
  __shared__ __align__(16) float At[32][68];
  __shared__ __align__(16) float Bt[32][64];
  int tid = threadIdx.x;
  int m0 = blockIdx.x << 6;
  int o0 = blockIdx.y << 6;
  int part = blockIdx.z;  // 0..2 -> dy = part-1
  int ti = tid >> 4, tj = tid & 15;   // compute tile 4x4
  int si = tid >> 2, sq = tid & 3;    // A staging: row si, col quad sq
  int skk = tid >> 3, sr = tid & 7;   // B staging: k-row skk, col oct sr
  float acc[4][4] = {{0.f}};

  int m = m0 + si;
  bool mv = m < NM;
  int mm = mv ? m : 0;
  int bb = mm / NPOS, rem = mm % NPOS;
  int hh = rem / HWDIM, ww = rem % HWDIM;
  int dy = part - 1;

  for (int tt = 0; tt < 3; tt++) {
    int tap = part * 3 + tt;
    int dx = tt - 1;
    int h2 = hh + dy, w2 = ww + dx;
    bool av = mv && ((unsigned)h2 < (unsigned)HWDIM) && ((unsigned)w2 < (unsigned)HWDIM);
    const float* arow = fm + (((size_t)(bb * NPOS + h2 * HWDIM + w2)) << 9);
    const float* bbase = Wt + (((size_t)tap) << 18) + o0;
    for (int c0 = 0; c0 < CIN; c0 += 32) {
      __syncthreads();
      float4 a0 = make_float4(0.f, 0.f, 0.f, 0.f), a1 = a0;
      if (av) {
        a0 = *(const float4*)(arow + c0 + (sq << 2));
        a1 = *(const float4*)(arow + c0 + 16 + (sq << 2));
      }
      int kb = sq << 2;
      At[kb + 0][si] = a0.x; At[kb + 1][si] = a0.y; At[kb + 2][si] = a0.z; At[kb + 3][si] = a0.w;
      At[kb + 16][si] = a1.x; At[kb + 17][si] = a1.y; At[kb + 18][si] = a1.z; At[kb + 19][si] = a1.w;
      const float* bp = bbase + (((size_t)(c0 + skk)) << 9);
      *(float4*)&Bt[skk][sr << 2] = *(const float4*)(bp + (sr << 2));
      *(float4*)&Bt[skk][32 + (sr << 2)] = *(const float4*)(bp + 32 + (sr << 2));
      __syncthreads();
#pragma unroll
      for (int kk = 0; kk < 32; kk++) {
        float4 avv = *(const float4*)&At[kk][ti << 2];
        float4 bvv = *(const float4*)&Bt[kk][tj << 2];
        float a_[4] = {avv.x, avv.y, avv.z, avv.w};
        float b_[4] = {bvv.x, bvv.y, bvv.z, bvv.w};
#pragma unroll
        for (int u = 0; u < 4; u++)
#pragma unroll
          for (int v = 0; v < 4; v++) acc[u][v] += a_[u] * b_[v];
      }
    }
  }
  float* outp = xp + (size_t)part * (NM * 512);
#pragma unroll
  for (int u = 0; u < 4; u++) {
    int mr = m0 + (ti << 2) + u;
    if (mr < NM) {
      float4 r = make_float4(acc[u][0], acc[u][1], acc[u][2], acc[u][3]);
      *(float4*)(outp + (((size_t)mr) << 9) + o0 + (tj << 2)) = r;
    }
  }
}

// x2 = relu(xp0+xp1+xp2+bias)
__global__ void combine_relu(const float* __restrict__ xp, const float* __restrict__ bias,
                             float* __restrict__ x2) {
  int i4 = blockIdx.x * 256 + threadIdx.x;  // over 320000 float4s
  if (i4 >= NM * 128) return;
  float4 p0 = *(const float4*)(xp + (size_t)i4 * 4);
  float4 p1 = *(const float4*)(xp + (size_t)(NM * 512) + (size_t)i4 * 4);
  float4 p2 = *(const float4*)(xp + (size_t)(2 * NM * 512) + (size_t)i4 * 4);
  float4 bb = *(const float4*)(bias + (i4 & 127) * 4);
  float4 r;
  r.x = fmaxf(p0.x + p1.x + p2.x + bb.x, 0.f);
  r.y = fmaxf(p0.y + p1.y + p2.y + bb.y, 0.f);
  r.z = fmaxf(p0.z + p1.z + p2.z + bb.z, 0.f);
  r.w = fmaxf(p0.w + p1.w + p2.w + bb.w, 0.f);
  *(float4*)(x2 + (size_t)i4 * 4) = r;
}

// --------------------------- 1x1 heads GEMM --------------------------------
// logits[m][0..63] = x2[m][:] @ Wco + bco   (grid 40)
__global__ __launch_bounds__(256) void gemm1x1(const float* __restrict__ x2,
                                               const float* __restrict__ Wco,
                                               const float* __restrict__ bco,
                                               float* __restrict__ logits) {
  __shared__ __align__(16) float At[32][68];
  __shared__ __align__(16) float Bt[32][64];
  int tid = threadIdx.x;
  int m0 = blockIdx.x << 6;
  int ti = tid >> 4, tj = tid & 15;
  int si = tid >> 2, sq = tid & 3;
  int skk = tid >> 3, sr = tid & 7;
  float acc[4][4] = {{0.f}};
  int m = m0 + si;
  bool mv = m < NM;
  const float* arow = x2 + (((size_t)(mv ? m : 0)) << 9);
  for (int c0 = 0; c0 < CIN; c0 += 32) {
    __syncthreads();
    float4 a0 = make_float4(0.f, 0.f, 0.f, 0.f), a1 = a0;
    if (mv) {
      a0 = *(const float4*)(arow + c0 + (sq << 2));
      a1 = *(const float4*)(arow + c0 + 16 + (sq << 2));
    }
    int kb = sq << 2;
    At[kb + 0][si] = a0.x; At[kb + 1][si] = a0.y; At[kb + 2][si] = a0.z; At[kb + 3][si] = a0.w;
    At[kb + 16][si] = a1.x; At[kb + 17][si] = a1.y; At[kb + 18][si] = a1.z; At[kb + 19][si] = a1.w;
    const float* bp = Wco + (size_t)(c0 + skk) * 64;
    *(float4*)&Bt[skk][sr << 2] = *(const float4*)(bp + (sr << 2));
    *(float4*)&Bt[skk][32 + (sr << 2)] = *(const float4*)(bp + 32 + (sr << 2));
    __syncthreads();
#pragma unroll
    for (int kk = 0; kk < 32; kk++) {
      float4 avv = *(const float4*)&At[kk][ti << 2];
      float4 bvv = *(const float4*)&Bt[kk][tj << 2];
      float a_[4] = {avv.x, avv.y, avv.z, avv.w};
      float b_[4] = {bvv.x, bvv.y, bvv.z, bvv.w};
#pragma unroll
      for (int u = 0; u < 4; u++)
#pragma unroll
        for (int v = 0; v < 4; v++) acc[u][v] += a_[u] * b_[v];
    }
  }
  float4 bias = *(const float4*)(bco + (tj << 2));
#pragma unroll
  for (int u = 0; u < 4; u++) {
    int mr = m0 + (ti << 2) + u;
    if (mr < NM) {
      float4 r = make_float4(acc[u][0] + bias.x, acc[u][1] + bias.y, acc[u][2] + bias.z,
                             acc[u][3] + bias.w);
      *(float4*)(logits + (size_t)mr * 64 + (tj << 2)) = r;
    }
  }
}

// --------------------------- scores + proposals ----------------------------
__global__ __launch_bounds__(256) void score_box_kernel(const float* __restrict__ logits,
                                                        const int* __restrict__ ih,
                                                        const int* __restrict__ iw,
                                                        BaseAnchors ba,
                                                        float* __restrict__ scores,
                                                        float* __restrict__ props) {
#pragma clang fp contract(off)
  int n = blockIdx.x * 256 + threadIdx.x;
  if (n >= NBATCH * NANCH) return;
  int b = n / NANCH;
  int r = n % NANCH;
  int pos = r / 9, aa = r % 9;
  int py = pos / HWDIM, px = pos % HWDIM;
  const float* L = logits + (size_t)(b * NPOS + pos) * 64;
  float l0 = L[2 * aa], l1 = L[2 * aa + 1];
  float mx = fmaxf(l0, l1);
  float e0 = expf(l0 - mx), e1 = expf(l1 - mx);
  float s = e1 / (e0 + e1);
  float d0 = L[18 + 4 * aa + 0], d1 = L[18 + 4 * aa + 1];
  float d2 = L[18 + 4 * aa + 2], d3 = L[18 + 4 * aa + 3];
  float xf = (float)px * 32.f, yf = (float)py * 32.f;
  float ax1 = ba.x1[aa] + xf, ay1 = ba.y1[aa] + yf;
  float ax2 = ba.x2[aa] + xf, ay2 = ba.y2[aa] + yf;
  float wA = ax2 - ax1, hA = ay2 - ay1;
  float cx = ax1 + 0.5f * wA, cy = ay1 + 0.5f * hA;
  float pcx = d0 * wA + cx, pcy = d1 * hA + cy;
  float pw = expf(d2) * wA, ph = expf(d3) * hA;
  float x1 = pcx - 0.5f * pw, y1 = pcy - 0.5f * ph;
  float x2 = pcx + 0.5f * pw, y2 = pcy + 0.5f * ph;
  float W = (float)iw[0], H = (float)ih[0];
  x1 = fminf(fmaxf(x1, 0.f), W);
  y1 = fminf(fmaxf(y1, 0.f), H);
  x2 = fminf(fmaxf(x2, 0.f), W);
  y2 = fminf(fmaxf(y2, 0.f), H);
  scores[n] = s;
  *(float4*)(props + (size_t)n * 4) = make_float4(x1, y1, x2, y2);
}

// --------------------------- sort (bitonic, stable ties) -------------------
__global__ __launch_bounds__(1024) void sort_kernel(const float* __restrict__ scores,
                                                    const float* __restrict__ props,
                                                    int* __restrict__ order,
                                                    float* __restrict__ sb) {
  __shared__ u64 keys[8192];
  int b = blockIdx.x, tid = threadIdx.x;
  const float* sc = scores + (size_t)b * NANCH;
  for (int i = tid; i < 8192; i += 1024) {
    u64 k = 0ull;
    if (i < NANCH) {
      unsigned int sbits = __float_as_uint(sc[i]);  // scores > 0 -> order-preserving bits
      k = (((u64)sbits) << 32) | (u64)(~(unsigned int)i);
    }
    keys[i] = k;
  }
  __syncthreads();
  for (int k = 2; k <= 8192; k <<= 1) {
    for (int j = k >> 1; j > 0; j >>= 1) {
#pragma unroll
      for (int s = 0; s < 8; s++) {
        int i = tid + (s << 10);
        int p = i ^ j;
        if (p > i) {
          u64 a = keys[i], c = keys[p];
          bool up = ((i & k) == 0);
          bool sw = up ? (a < c) : (a > c);  // descending overall
          if (sw) { keys[i] = c; keys[p] = a; }
        }
      }
      __syncthreads();
    }
  }
  for (int i = tid; i < NANCH; i += 1024) {
    u64 kk = keys[i];
    int orig = (int)(~(unsigned int)kk);
    order[b * NANCH + i] = orig;
    float4 p = *(const float4*)(props + ((size_t)b * NANCH + orig) * 4);
    *(float4*)(sb + ((size_t)b * NANCH + i) * 4) = p;
  }
}

// --------------------------- NMS bitmask -----------------------------------
// Row-major mask[b][row i][word cb] (bit l = suppress col j=cb*64+l, j>i).
// Diagonal blocks (rb==cb) additionally stored coalesced in maskd[b][s][lane].
__global__ __launch_bounds__(64) void nms_mask_kernel(const float* __restrict__ sb,
                                                      u64* __restrict__ mask,
                                                      u64* __restrict__ maskd) {
#pragma clang fp contract(off)
  int rb = blockIdx.x, cb = blockIdx.y, b = blockIdx.z;
  if (cb < rb) return;
  int lane = threadIdx.x;
  __shared__ float4 cbox[64];
  int j0 = cb << 6;
  const float* sbb = sb + (size_t)b * NANCH * 4;
  if (j0 + lane < NANCH) cbox[lane] = *(const float4*)(sbb + (size_t)(j0 + lane) * 4);
  __syncthreads();
  int i = (rb << 6) + lane;
  if (i >= NANCH) return;
  float4 rbox = *(const float4*)(sbb + (size_t)i * 4);
  float rarea = (rbox.z - rbox.x) * (rbox.w - rbox.y);
  u64 bits = 0ull;
  int jmax = NANCH - j0;
  if (jmax > 64) jmax = 64;
  for (int l = 0; l < jmax; l++) {
    int j = j0 + l;
    if (j > i) {
      float4 c = cbox[l];
      float carea = (c.z - c.x) * (c.w - c.y);
      float ltx = fmaxf(rbox.x, c.x), lty = fmaxf(rbox.y, c.y);
      float rbx = fminf(rbox.z, c.z), rby = fminf(rbox.w, c.w);
      float wx = fmaxf(rbx - ltx, 0.f);
      float wy = fmaxf(rby - lty, 0.f);
      float inter = wx * wy;
      float iou = inter / (rarea + carea - inter);  // 0/0 -> NaN -> compare false
      if (iou > 0.7f) bits |= (1ull << l);
    }
  }
  mask[((size_t)b * NANCH + i) * NW + cb] = bits;
  if (rb == cb) maskd[((size_t)b * NW + rb) * 64 + lane] = bits;
}

// --------------------------- NMS scan (incremental, forced-MLP) ------------
// One wave per batch. Lane l (l<44) owns remv words 2l (rv0) and 2l+1 (rv1).
// Per stripe s: cur = readlane of word s (no memory); ctz chain over the
// coalesced diagonal word decides alive rows; then alive rows' full mask rows
// are OR'd into rv via batches of 8 global_load_dwordx4 in ONE asm block with
// in-block s_waitcnt (forces 8 loads in flight; plain loads got serialized).
__global__ __launch_bounds__(64, 1) void nms_scan_kernel(const u64* __restrict__ mask,
                                                         const u64* __restrict__ maskd,
                                                         const int* __restrict__ order,
                                                         const float* __restrict__ sb,
                                                         float* __restrict__ out) {
  int b = blockIdx.x;
  int lane = threadIdx.x;
  const u64* mb = mask + (size_t)b * NANCH * NW;
  const u64* md = maskd + (size_t)b * NW * 64;
  u64 rv0 = 0ull, rv1 = 0ull;  // remv words 2*lane, 2*lane+1 (lanes 0..43)
  int lc = lane < 44 ? lane : 43;  // clamped for safe (discarded) loads
  __shared__ u64 keep_lds[NW];

  u64 diag = md[lane];  // stripe 0 diagonal (coalesced)
  for (int s = 0; s < NW; s++) {
    int r0 = s << 6;
    int nrows = NANCH - r0;
    if (nrows > 64) nrows = 64;
    u64 Mw = diag;
    if (s + 1 < NW) diag = md[((s + 1) << 6) + lane];  // prefetch next

    u64 cur = bcast64((s & 1) ? rv1 : rv0, s >> 1);
    u64 todo = ~cur;
    if (nrows < 64) todo &= (1ull << nrows) - 1ull;
    u64 alive = 0ull;
    while (todo) {
      int t = (int)__builtin_ctzll(todo);
      alive |= (1ull << t);
      todo &= ~(bcast64(Mw, t) | (1ull << t));
    }
    if (lane == 0) keep_lds[s] = alive;

    // OR alive rows' mask rows into rv, 8 rows per forced-MLP batch.
    u64 aw = alive;
    while (aw) {
      int t0 = (int)__builtin_ctzll(aw); aw &= aw - 1;
      int t1 = aw ? (int)__builtin_ctzll(aw) : t0; aw &= aw - 1;
      int t2 = aw ? (int)__builtin_ctzll(aw) : t0; aw &= aw - 1;
      int t3 = aw ? (int)__builtin_ctzll(aw) : t0; aw &= aw - 1;
      int t4 = aw ? (int)__builtin_ctzll(aw) : t0; aw &= aw - 1;
      int t5 = aw ? (int)__builtin_ctzll(aw) : t0; aw &= aw - 1;
      int t6 = aw ? (int)__builtin_ctzll(aw) : t0; aw &= aw - 1;
      int t7 = aw ? (int)__builtin_ctzll(aw) : t0; aw &= aw - 1;
      const u64* a0 = mb + (size_t)(r0 + t0) * NW + (lc << 1);
      const u64* a1 = mb + (size_t)(r0 + t1) * NW + (lc << 1);
      const u64* a2 = mb + (size_t)(r0 + t2) * NW + (lc << 1);
      const u64* a3 = mb + (size_t)(r0 + t3) * NW + (lc << 1);
      const u64* a4 = mb + (size_t)(r0 + t4) * NW + (lc << 1);
      const u64* a5 = mb + (size_t)(r0 + t5) * NW + (lc << 1);
      const u64* a6 = mb + (size_t)(r0 + t6) * NW + (lc << 1);
      const u64* a7 = mb + (size_t)(r0 + t7) * NW + (lc << 1);
      uint4v x0, x1, x2, x3, x4, x5, x6, x7;
      asm volatile(
          "global_load_dwordx4 %0, %8, off\n\t"
          "global_load_dwordx4 %1, %9, off\n\t"
          "global_load_dwordx4 %2, %10, off\n\t"
          "global_load_dwordx4 %3, %11, off\n\t"
          "global_load_dwordx4 %4, %12, off\n\t"
          "global_load_dwordx4 %5, %13, off\n\t"
          "global_load_dwordx4 %6, %14, off\n\t"
          "global_load_dwordx4 %7, %15, off\n\t"
          "s_waitcnt vmcnt(0)"
          : "=&v"(x0), "=&v"(x1), "=&v"(x2), "=&v"(x3),
            "=&v"(x4), "=&v"(x5), "=&v"(x6), "=&v"(x7)
          : "v"(a0), "v"(a1), "v"(a2), "v"(a3),
            "v"(a4), "v"(a5), "v"(a6), "v"(a7)
          : "memory");
      rv0 |= pk_lo(x0) | pk_lo(x1) | pk_lo(x2) | pk_lo(x3) |
             pk_lo(x4) | pk_lo(x5) | pk_lo(x6) | pk_lo(x7);
      rv1 |= pk_hi(x0) | pk_hi(x1) | pk_hi(x2) | pk_hi(x3) |
             pk_hi(x4) | pk_hi(x5) | pk_hi(x6) | pk_hi(x7);
    }
  }
  __syncthreads();
  // write output: out[b][orig] = kept ? sorted_box : 0
  for (int i = lane; i < NANCH; i += 64) {
    u64 kw = keep_lds[i >> 6];
    bool kept = ((kw >> (i & 63)) & 1ull) != 0ull;
    int orig = order[b * NANCH + i];
    float4 p = *(const float4*)(sb + ((size_t)b * NANCH + i) * 4);
    float4 o = kept ? p : make_float4(0.f, 0.f, 0.f, 0.f);
    *(float4*)(out + ((size_t)b * NANCH + orig) * 4) = o;
  }
}

// --------------------------- host launcher ---------------------------------

extern "C" void kernel_launch(void* const* d_in, const int* in_sizes, int n_in,
                              void* d_out, int out_size, void* d_ws, size_t ws_size,
                              hipStream_t stream) {
  const float* features = (const float*)d_in[0];
  const float* conv_w   = (const float*)d_in[1];
  const float* conv_b   = (const float*)d_in[2];
  const float* cls_w    = (const float*)d_in[3];
  const float* cls_b    = (const float*)d_in[4];
  const float* bbox_w   = (const float*)d_in[5];
  const float* bbox_b   = (const float*)d_in[6];
  const int*   img_h    = (const int*)d_in[7];
  const int*   img_w    = (const int*)d_in[8];
  float* out = (float*)d_out;
  char* ws = (char*)d_ws;

  // workspace layout (bytes); MASK/MASKD alias FM/WT/XP which are dead by then
  const size_t OFF_FM  = 0;                    // 5,120,000
  const size_t OFF_WT  = 5120000;              // 9,437,184
  const size_t OFF_XP  = 14557184;             // 15,360,000
  const size_t OFF_MASK  = 0;                  // 15,840,000 (aliases FM..XP)
  const size_t OFF_MASKD = 15840000;           // 180,224 (still inside dead XP)
  const size_t OFF_X2  = 29917184;             // 5,120,000
  const size_t OFF_WCO = 35037184;             // 131,072
  const size_t OFF_BCO = 35168256;             // 256
  const size_t OFF_LOG = 35168512;             // 640,000
  const size_t OFF_SC  = 35808512;             // 90,000
  const size_t OFF_PR  = 35898512;             // 360,000
  const size_t OFF_ORD = 36258512;             // 90,000
  const size_t OFF_SB  = 36348512;             // 360,000
  const size_t WS_NEEDED = 36708512;
  if (ws_size < WS_NEEDED) return;

  float* fm   = (float*)(ws + OFF_FM);
  float* Wt   = (float*)(ws + OFF_WT);
  float* xp   = (float*)(ws + OFF_XP);
  u64*   mask  = (u64*)(ws + OFF_MASK);
  u64*   maskd = (u64*)(ws + OFF_MASKD);
  float* x2   = (float*)(ws + OFF_X2);
  float* Wco  = (float*)(ws + OFF_WCO);
  float* bco  = (float*)(ws + OFF_BCO);
  float* logits = (float*)(ws + OFF_LOG);
  float* scores = (float*)(ws + OFF_SC);
  float* props  = (float*)(ws + OFF_PR);
  int*   order  = (int*)(ws + OFF_ORD);
  float* sb     = (float*)(ws + OFF_SB);

  // base anchors in double, rounded to f32 exactly like numpy
  BaseAnchors ba;
  {
    const double scales[3] = {64.0, 128.0, 256.0};
    const double ratios[3] = {0.5, 1.0, 2.0};
    int a = 0;
    for (int si = 0; si < 3; si++)
      for (int ri = 0; ri < 3; ri++, a++) {
        double w = scales[si] * sqrt(ratios[ri]);
        double h = scales[si] / sqrt(ratios[ri]);
        ba.x1[a] = (float)(-w / 2.0);
        ba.y1[a] = (float)(-h / 2.0);
        ba.x2[a] = (float)(w / 2.0);
        ba.y2[a] = (float)(h / 2.0);
      }
  }

  transpose_features<<<dim3(20, 16, 4), dim3(32, 8), 0, stream>>>(features, fm);
  transpose_weights<<<dim3(16, 16), 256, 0, stream>>>(conv_w, Wt);
  build_wco<<<128, 256, 0, stream>>>(cls_w, cls_b, bbox_w, bbox_b, Wco, bco);
  conv_gemm<<<dim3(40, 8, 3), 256, 0, stream>>>(fm, Wt, xp);
  combine_relu<<<1250, 256, 0, stream>>>(xp, conv_b, x2);
  gemm1x1<<<40, 256, 0, stream>>>(x2, Wco, bco, logits);
  score_box_kernel<<<88, 256, 0, stream>>>(logits, img_h, img_w, ba, scores, props);
  sort_kernel<<<4, 1024, 0, stream>>>(scores, props, order, sb);
  nms_mask_kernel<<<dim3(NW, NW, 4), 64, 0, stream>>>(sb, mask, maskd);
  nms_scan_kernel<<<4, 64, 0, stream>>>(mask, maskd, order, sb, out);
}

// Round 6
// 743.508 us; speedup vs baseline: 1.3648x; 1.0825x over previous
//
#include <hip/hip_runtime.h>

// ---------------------------------------------------------------------------
// RPN forward: conv3x3(512->512)+relu, 1x1 heads (18 cls, 36 bbox),
// anchor decode + clip, softmax score, greedy NMS (0.7), keep-masked boxes.
// All decision math in fp32 with contraction OFF to track the numpy reference.
// R6 scan: 16-wave block per batch (TLP instead of ILP). Transposed u64 mask
//   maskT[b][word][row]; per stripe, waves gather disjoint chunk sets of
//   column s (coalesced, keep-bit-masked), LDS combine, wave 0 runs the ctz
//   chain on LDS-preloaded diagonals. Plain loads + barriers only.
//   History: R1 v[64]->scratch 517us; R2/R3 in-wave loads serialized ~330cy
//   each 655/536us; R4 asm 8-deep batches 434us (680 round-trips, K~5100
//   alive); R5 global_load_lds same-wave readback FAILED correctness (648).
// ---------------------------------------------------------------------------

#define NBATCH 4
#define HWDIM  25
#define NPOS   625            // 25*25
#define NM     2500           // NBATCH*NPOS
#define CIN    512
#define NANCH  5625           // NPOS*9
#define NW     88             // ceil(NANCH/64)
#define RSTR   5632           // row stride (64-aligned) for transposed mask
#define NWAVES 16

typedef unsigned long long u64;
typedef unsigned int u32;

struct BaseAnchors { float x1[9], y1[9], x2[9], y2[9]; };

__device__ __forceinline__ u64 bcast64(u64 v, int lane) {
  unsigned int lo = (unsigned int)v;
  unsigned int hi = (unsigned int)(v >> 32);
  lo = (unsigned int)__builtin_amdgcn_readlane((int)lo, lane);
  hi = (unsigned int)__builtin_amdgcn_readlane((int)hi, lane);
  return (((u64)hi) << 32) | (u64)lo;
}

__device__ __forceinline__ u64 waveOr64(u64 x) {
  unsigned int lo = (unsigned int)x, hi = (unsigned int)(x >> 32);
#pragma unroll
  for (int off = 32; off > 0; off >>= 1) {
    lo |= (unsigned int)__shfl_xor((int)lo, off, 64);
    hi |= (unsigned int)__shfl_xor((int)hi, off, 64);
  }
  return (((u64)hi) << 32) | (u64)lo;
}

// --------------------------- prep: transposes ------------------------------

// f[b][c][pos] -> fm[b*625+pos][c]
__global__ void transpose_features(const float* __restrict__ f, float* __restrict__ fm) {
  __shared__ float tile[32][33];
  int b  = blockIdx.z;
  int p0 = blockIdx.x * 32;
  int c0 = blockIdx.y * 32;
  int tx = threadIdx.x, ty = threadIdx.y;  // (32, 8)
#pragma unroll
  for (int j = 0; j < 4; j++) {
    int c = c0 + ty + j * 8;
    int p = p0 + tx;
    if (p < NPOS) tile[ty + j * 8][tx] = f[((size_t)(b * CIN + c)) * NPOS + p];
  }
  __syncthreads();
#pragma unroll
  for (int j = 0; j < 4; j++) {
    int p = p0 + ty + j * 8;
    int c = c0 + tx;
    if (p < NPOS) fm[((size_t)(b * NPOS + p)) * CIN + c] = tile[tx][ty + j * 8];
  }
}

// conv_w[o][c][tap] -> Wt[tap][c][o]
__global__ __launch_bounds__(256) void transpose_weights(const float* __restrict__ cw,
                                                         float* __restrict__ Wt) {
  __shared__ float tile[32][289];
  int o0 = blockIdx.x * 32, c0 = blockIdx.y * 32;
  int tid = threadIdx.x;
#pragma unroll
  for (int j = 0; j < 36; j++) {
    int idx = tid + j * 256;            // 0..9215
    int o = idx / 288, kk = idx % 288;  // kk = c_rel*9 + tap
    tile[o][kk] = cw[((size_t)(o0 + o)) * 4608 + c0 * 9 + kk];
  }
  __syncthreads();
  int ol = tid & 31, pg = tid >> 5;  // 0..7
#pragma unroll
  for (int j = 0; j < 36; j++) {
    int pair = pg + j * 8;  // 0..287 == c_rel*9 + tap
    int c = pair / 9, tap = pair % 9;
    Wt[((size_t)tap * CIN + (c0 + c)) * 512 + o0 + ol] = tile[ol][pair];
  }
}

// combined 1x1 head weights: Wco[c][o] (o: 0..17 cls, 18..53 bbox, 54..63 zero)
__global__ void build_wco(const float* __restrict__ clsw, const float* __restrict__ clsb,
                          const float* __restrict__ bw, const float* __restrict__ bbb,
                          float* __restrict__ Wco, float* __restrict__ bco) {
  int idx = blockIdx.x * 256 + threadIdx.x;
  if (idx < 512 * 64) {
    int c = idx >> 6, o = idx & 63;
    float v = 0.f;
    if (o < 18) v = clsw[o * 512 + c];
    else if (o < 54) v = bw[(o - 18) * 512 + c];
    Wco[idx] = v;
  }
  if (idx < 64) {
    float v = 0.f;
    if (idx < 18) v = clsb[idx];
    else if (idx < 54) v = bbb[idx - 18];
    bco[idx] = v;
  }
}

// --------------------------- conv3x3 implicit GEMM -------------------------
// grid (40, 8, 3): 64 m-rows x 64 o-cols per block, part = 3 taps (dy fixed).
// Writes partial sums (no bias/relu) to xp[part][m][o].
__global__ __launch_bounds__(256) void conv_gemm(const float* __restrict__ fm,
                                                 const float* __restrict__ Wt,
                                                 float* __restrict__ xp) {
  __shared__ __align__(16) float At[32][68];
  __shared__ __align__(16) float Bt[32][64];
  int tid = threadIdx.x;
  int m0 = blockIdx.x << 6;
  int o0 = blockIdx.y << 6;
  int part = blockIdx.z;  // 0..2 -> dy = part-1
  int ti = tid >> 4, tj = tid & 15;   // compute tile 4x4
  int si = tid >> 2, sq = tid & 3;    // A staging: row si, col quad sq
  int skk = tid >> 3, sr = tid & 7;   // B staging: k-row skk, col oct sr
  float acc[4][4] = {{0.f}};

  int m = m0 + si;
  bool mv = m < NM;
  int mm = mv ? m : 0;
  int bb = mm / NPOS, rem = mm % NPOS;
  int hh = rem / HWDIM, ww = rem % HWDIM;
  int dy = part - 1;

  for (int tt = 0; tt < 3; tt++) {
    int tap = part * 3 + tt;
    int dx = tt - 1;
    int h2 = hh + dy, w2 = ww + dx;
    bool av = mv && ((unsigned)h2 < (unsigned)HWDIM) && ((unsigned)w2 < (unsigned)HWDIM);
    const float* arow = fm + (((size_t)(bb * NPOS + h2 * HWDIM + w2)) << 9);
    const float* bbase = Wt + (((size_t)tap) << 18) + o0;
    for (int c0 = 0; c0 < CIN; c0 += 32) {
      __syncthreads();
      float4 a0 = make_float4(0.f, 0.f, 0.f, 0.f), a1 = a0;
      if (av) {
        a0 = *(const float4*)(arow + c0 + (sq << 2));
        a1 = *(const float4*)(arow + c0 + 16 + (sq << 2));
      }
      int kb = sq << 2;
      At[kb + 0][si] = a0.x; At[kb + 1][si] = a0.y; At[kb + 2][si] = a0.z; At[kb + 3][si] = a0.w;
      At[kb + 16][si] = a1.x; At[kb + 17][si] = a1.y; At[kb + 18][si] = a1.z; At[kb + 19][si] = a1.w;
      const float* bp = bbase + (((size_t)(c0 + skk)) << 9);
      *(float4*)&Bt[skk][sr << 2] = *(const float4*)(bp + (sr << 2));
      *(float4*)&Bt[skk][32 + (sr << 2)] = *(const float4*)(bp + 32 + (sr << 2));
      __syncthreads();
#pragma unroll
      for (int kk = 0; kk < 32; kk++) {
        float4 avv = *(const float4*)&At[kk][ti << 2];
        float4 bvv = *(const float4*)&Bt[kk][tj << 2];
        float a_[4] = {avv.x, avv.y, avv.z, avv.w};
        float b_[4] = {bvv.x, bvv.y, bvv.z, bvv.w};
#pragma unroll
        for (int u = 0; u < 4; u++)
#pragma unroll
          for (int v = 0; v < 4; v++) acc[u][v] += a_[u] * b_[v];
      }
    }
  }
  float* outp = xp + (size_t)part * (NM * 512);
#pragma unroll
  for (int u = 0; u < 4; u++) {
    int mr = m0 + (ti << 2) + u;
    if (mr < NM) {
      float4 r = make_float4(acc[u][0], acc[u][1], acc[u][2], acc[u][3]);
      *(float4*)(outp + (((size_t)mr) << 9) + o0 + (tj << 2)) = r;
    }
  }
}

// x2 = relu(xp0+xp1+xp2+bias)
__global__ void combine_relu(const float* __restrict__ xp, const float* __restrict__ bias,
                             float* __restrict__ x2) {
  int i4 = blockIdx.x * 256 + threadIdx.x;  // over 320000 float4s
  if (i4 >= NM * 128) return;
  float4 p0 = *(const float4*)(xp + (size_t)i4 * 4);
  float4 p1 = *(const float4*)(xp + (size_t)(NM * 512) + (size_t)i4 * 4);
  float4 p2 = *(const float4*)(xp + (size_t)(2 * NM * 512) + (size_t)i4 * 4);
  float4 bb = *(const float4*)(bias + (i4 & 127) * 4);
  float4 r;
  r.x = fmaxf(p0.x + p1.x + p2.x + bb.x, 0.f);
  r.y = fmaxf(p0.y + p1.y + p2.y + bb.y, 0.f);
  r.z = fmaxf(p0.z + p1.z + p2.z + bb.z, 0.f);
  r.w = fmaxf(p0.w + p1.w + p2.w + bb.w, 0.f);
  *(float4*)(x2 + (size_t)i4 * 4) = r;
}

// --------------------------- 1x1 heads GEMM --------------------------------
// logits[m][0..63] = x2[m][:] @ Wco + bco   (grid 40)
__global__ __launch_bounds__(256) void gemm1x1(const float* __restrict__ x2,
                                               const float* __restrict__ Wco,
                                               const float* __restrict__ bco,
                                               float* __restrict__ logits) {
  __shared__ __align__(16) float At[32][68];
  __shared__ __align__(16) float Bt[32][64];
  int tid = threadIdx.x;
  int m0 = blockIdx.x << 6;
  int ti = tid >> 4, tj = tid & 15;
  int si = tid >> 2, sq = tid & 3;
  int skk = tid >> 3, sr = tid & 7;
  float acc[4][4] = {{0.f}};
  int m = m0 + si;
  bool mv = m < NM;
  const float* arow = x2 + (((size_t)(mv ? m : 0)) << 9);
  for (int c0 = 0; c0 < CIN; c0 += 32) {
    __syncthreads();
    float4 a0 = make_float4(0.f, 0.f, 0.f, 0.f), a1 = a0;
    if (mv) {
      a0 = *(const float4*)(arow + c0 + (sq << 2));
      a1 = *(const float4*)(arow + c0 + 16 + (sq << 2));
    }
    int kb = sq << 2;
    At[kb + 0][si] = a0.x; At[kb + 1][si] = a0.y; At[kb + 2][si] = a0.z; At[kb + 3][si] = a0.w;
    At[kb + 16][si] = a1.x; At[kb + 17][si] = a1.y; At[kb + 18][si] = a1.z; At[kb + 19][si] = a1.w;
    const float* bp = Wco + (size_t)(c0 + skk) * 64;
    *(float4*)&Bt[skk][sr << 2] = *(const float4*)(bp + (sr << 2));
    *(float4*)&Bt[skk][32 + (sr << 2)] = *(const float4*)(bp + 32 + (sr << 2));
    __syncthreads();
#pragma unroll
    for (int kk = 0; kk < 32; kk++) {
      float4 avv = *(const float4*)&At[kk][ti << 2];
      float4 bvv = *(const float4*)&Bt[kk][tj << 2];
      float a_[4] = {avv.x, avv.y, avv.z, avv.w};
      float b_[4] = {bvv.x, bvv.y, bvv.z, bvv.w};
#pragma unroll
      for (int u = 0; u < 4; u++)
#pragma unroll
        for (int v = 0; v < 4; v++) acc[u][v] += a_[u] * b_[v];
    }
  }
  float4 bias = *(const float4*)(bco + (tj << 2));
#pragma unroll
  for (int u = 0; u < 4; u++) {
    int mr = m0 + (ti << 2) + u;
    if (mr < NM) {
      float4 r = make_float4(acc[u][0] + bias.x, acc[u][1] + bias.y, acc[u][2] + bias.z,
                             acc[u][3] + bias.w);
      *(float4*)(logits + (size_t)mr * 64 + (tj << 2)) = r;
    }
  }
}

// --------------------------- scores + proposals ----------------------------
__global__ __launch_bounds__(256) void score_box_kernel(const float* __restrict__ logits,
                                                        const int* __restrict__ ih,
                                                        const int* __restrict__ iw,
                                                        BaseAnchors ba,
                                                        float* __restrict__ scores,
                                                        float* __restrict__ props) {
#pragma clang fp contract(off)
  int n = blockIdx.x * 256 + threadIdx.x;
  if (n >= NBATCH * NANCH) return;
  int b = n / NANCH;
  int r = n % NANCH;
  int pos = r / 9, aa = r % 9;
  int py = pos / HWDIM, px = pos % HWDIM;
  const float* L = logits + (size_t)(b * NPOS + pos) * 64;
  float l0 = L[2 * aa], l1 = L[2 * aa + 1];
  float mx = fmaxf(l0, l1);
  float e0 = expf(l0 - mx), e1 = expf(l1 - mx);
  float s = e1 / (e0 + e1);
  float d0 = L[18 + 4 * aa + 0], d1 = L[18 + 4 * aa + 1];
  float d2 = L[18 + 4 * aa + 2], d3 = L[18 + 4 * aa + 3];
  float xf = (float)px * 32.f, yf = (float)py * 32.f;
  float ax1 = ba.x1[aa] + xf, ay1 = ba.y1[aa] + yf;
  float ax2 = ba.x2[aa] + xf, ay2 = ba.y2[aa] + yf;
  float wA = ax2 - ax1, hA = ay2 - ay1;
  float cx = ax1 + 0.5f * wA, cy = ay1 + 0.5f * hA;
  float pcx = d0 * wA + cx, pcy = d1 * hA + cy;
  float pw = expf(d2) * wA, ph = expf(d3) * hA;
  float x1 = pcx - 0.5f * pw, y1 = pcy - 0.5f * ph;
  float x2 = pcx + 0.5f * pw, y2 = pcy + 0.5f * ph;
  float W = (float)iw[0], H = (float)ih[0];
  x1 = fminf(fmaxf(x1, 0.f), W);
  y1 = fminf(fmaxf(y1, 0.f), H);
  x2 = fminf(fmaxf(x2, 0.f), W);
  y2 = fminf(fmaxf(y2, 0.f), H);
  scores[n] = s;
  *(float4*)(props + (size_t)n * 4) = make_float4(x1, y1, x2, y2);
}

// --------------------------- sort (bitonic, stable ties) -------------------
__global__ __launch_bounds__(1024) void sort_kernel(const float* __restrict__ scores,
                                                    const float* __restrict__ props,
                                                    int* __restrict__ order,
                                                    float* __restrict__ sb) {
  __shared__ u64 keys[8192];
  int b = blockIdx.x, tid = threadIdx.x;
  const float* sc = scores + (size_t)b * NANCH;
  for (int i = tid; i < 8192; i += 1024) {
    u64 k = 0ull;
    if (i < NANCH) {
      unsigned int sbits = __float_as_uint(sc[i]);  // scores > 0 -> order-preserving bits
      k = (((u64)sbits) << 32) | (u64)(~(unsigned int)i);
    }
    keys[i] = k;
  }
  __syncthreads();
  for (int k = 2; k <= 8192; k <<= 1) {
    for (int j = k >> 1; j > 0; j >>= 1) {
#pragma unroll
      for (int s = 0; s < 8; s++) {
        int i = tid + (s << 10);
        int p = i ^ j;
        if (p > i) {
          u64 a = keys[i], c = keys[p];
          bool up = ((i & k) == 0);
          bool sw = up ? (a < c) : (a > c);  // descending overall
          if (sw) { keys[i] = c; keys[p] = a; }
        }
      }
      __syncthreads();
    }
  }
  for (int i = tid; i < NANCH; i += 1024) {
    u64 kk = keys[i];
    int orig = (int)(~(unsigned int)kk);
    order[b * NANCH + i] = orig;
    float4 p = *(const float4*)(props + ((size_t)b * NANCH + orig) * 4);
    *(float4*)(sb + ((size_t)b * NANCH + i) * 4) = p;
  }
}

// --------------------------- NMS bitmask (transposed u64) ------------------
// maskT[b][word cb][row i] (bit l = suppress col j=cb*64+l by row i, j>i);
// coalesced 8B-stride stores. Diagonals also in maskd[b][s][lane].
__global__ __launch_bounds__(64) void nms_mask_kernel(const float* __restrict__ sb,
                                                      u64* __restrict__ maskT,
                                                      u64* __restrict__ maskd) {
#pragma clang fp contract(off)
  int rb = blockIdx.x, cb = blockIdx.y, b = blockIdx.z;
  if (cb < rb) return;
  int lane = threadIdx.x;
  __shared__ float4 cbox[64];
  int j0 = cb << 6;
  const float* sbb = sb + (size_t)b * NANCH * 4;
  if (j0 + lane < NANCH) cbox[lane] = *(const float4*)(sbb + (size_t)(j0 + lane) * 4);
  __syncthreads();
  int i = (rb << 6) + lane;
  if (i >= NANCH) return;
  float4 rbox = *(const float4*)(sbb + (size_t)i * 4);
  float rarea = (rbox.z - rbox.x) * (rbox.w - rbox.y);
  u64 bits = 0ull;
  int jmax = NANCH - j0;
  if (jmax > 64) jmax = 64;
  for (int l = 0; l < jmax; l++) {
    int j = j0 + l;
    if (j > i) {
      float4 c = cbox[l];
      float carea = (c.z - c.x) * (c.w - c.y);
      float ltx = fmaxf(rbox.x, c.x), lty = fmaxf(rbox.y, c.y);
      float rbx = fminf(rbox.z, c.z), rby = fminf(rbox.w, c.w);
      float wx = fmaxf(rbx - ltx, 0.f);
      float wy = fmaxf(rby - lty, 0.f);
      float inter = wx * wy;
      float iou = inter / (rarea + carea - inter);  // 0/0 -> NaN -> compare false
      if (iou > 0.7f) bits |= (1ull << l);
    }
  }
  maskT[((size_t)b * NW + cb) * RSTR + i] = bits;
  if (rb == cb) maskd[((size_t)b * NW + rb) * 64 + lane] = bits;
}

// --------------------------- NMS scan (16-wave TLP) -------------------------
// One 1024-thread block per batch. Per stripe s, the only suppression word
// needed is word s: cur = OR over alive prior rows r<64s of maskT[s][r].
// Wave w gathers chunks c in {w, w+16, ...} < s (64-lane coalesced u64 loads,
// masked by keep bit from LDS), wave-reduces, then wave 0 combines the 16
// partials and runs the ctz chain on the LDS-preloaded diagonal word.
__global__ __launch_bounds__(1024, 1) void nms_scan_kernel(const u64* __restrict__ maskT,
                                                           const u64* __restrict__ maskd,
                                                           const int* __restrict__ order,
                                                           const float* __restrict__ sb,
                                                           float* __restrict__ out) {
  int b = blockIdx.x;
  int tid = threadIdx.x;
  int lane = tid & 63, wv = tid >> 6;
  const u64* mt = maskT + (size_t)b * NW * RSTR;
  __shared__ u64 diag_sh[NW * 64];   // 45056 B: all diagonal words
  __shared__ u64 keep_sh[NW];
  __shared__ u64 cur_parts[NWAVES];

  // preload diagonals (coalesced, parallel)
  for (int i = tid; i < NW * 64; i += 1024)
    diag_sh[i] = maskd[(size_t)b * NW * 64 + i];
  __syncthreads();

  for (int s = 0; s < NW; s++) {
    // ---- parallel gather of column s over prior chunks (keep-masked) ----
    u64 acc = 0ull;
    const u64* col = mt + (size_t)s * RSTR + lane;
    for (int c = wv; c < s; c += NWAVES) {
      u64 v = col[c << 6];          // row c*64+lane, word s (coalesced)
      u64 kw = keep_sh[c];          // keep word of stripe c (LDS broadcast)
      if ((kw >> lane) & 1ull) acc |= v;
    }
    acc = waveOr64(acc);
    if (lane == 0) cur_parts[wv] = acc;
    __syncthreads();

    // ---- wave 0: combine partials + serial ctz chain ----
    if (wv == 0) {
      u64 p = (lane < NWAVES) ? cur_parts[lane] : 0ull;
      u64 cur = waveOr64(p);
      u64 Mw = diag_sh[(s << 6) + lane];  // row 64s+lane, word s
      int nrows = NANCH - (s << 6);
      if (nrows > 64) nrows = 64;
      u64 todo = ~cur;
      if (nrows < 64) todo &= (1ull << nrows) - 1ull;
      u64 alive = 0ull;
      while (todo) {
        int t = (int)__builtin_ctzll(todo);
        alive |= (1ull << t);
        todo &= ~(bcast64(Mw, t) | (1ull << t));
      }
      if (lane == 0) keep_sh[s] = alive;
    }
    __syncthreads();
  }

  // write output: out[b][orig] = kept ? sorted_box : 0
  for (int i = tid; i < NANCH; i += 1024) {
    u64 kw = keep_sh[i >> 6];
    bool kept = ((kw >> (i & 63)) & 1ull) != 0ull;
    int orig = order[b * NANCH + i];
    float4 p = *(const float4*)(sb + ((size_t)b * NANCH + i) * 4);
    float4 o = kept ? p : make_float4(0.f, 0.f, 0.f, 0.f);
    *(float4*)(out + ((size_t)b * NANCH + orig) * 4) = o;
  }
}

// --------------------------- host launcher ---------------------------------

extern "C" void kernel_launch(void* const* d_in, const int* in_sizes, int n_in,
                              void* d_out, int out_size, void* d_ws, size_t ws_size,
                              hipStream_t stream) {
  const float* features = (const float*)d_in[0];
  const float* conv_w   = (const float*)d_in[1];
  const float* conv_b   = (const float*)d_in[2];
  const float* cls_w    = (const float*)d_in[3];
  const float* cls_b    = (const float*)d_in[4];
  const float* bbox_w   = (const float*)d_in[5];
  const float* bbox_b   = (const float*)d_in[6];
  const int*   img_h    = (const int*)d_in[7];
  const int*   img_w    = (const int*)d_in[8];
  float* out = (float*)d_out;
  char* ws = (char*)d_ws;

  // workspace layout (bytes); mask arrays alias FM/WT/XP (dead by NMS time)
  const size_t OFF_FM    = 0;                  // 5,120,000
  const size_t OFF_WT    = 5120000;            // 9,437,184
  const size_t OFF_XP    = 14557184;           // 15,360,000 (ends 29,917,184)
  const size_t OFF_MASKT = 0;                  // 15,859,712 (aliases FM/WT/XP-head)
  const size_t OFF_MASKD = 15859712;           // 180,224 (inside dead XP)
  const size_t OFF_X2  = 29917184;             // 5,120,000
  const size_t OFF_WCO = 35037184;             // 131,072
  const size_t OFF_BCO = 35168256;             // 256
  const size_t OFF_LOG = 35168512;             // 640,000
  const size_t OFF_SC  = 35808512;             // 90,000
  const size_t OFF_PR  = 35898512;             // 360,000
  const size_t OFF_ORD = 36258512;             // 90,000
  const size_t OFF_SB  = 36348512;             // 360,000
  const size_t WS_NEEDED = 36708512;
  if (ws_size < WS_NEEDED) return;

  float* fm   = (float*)(ws + OFF_FM);
  float* Wt   = (float*)(ws + OFF_WT);
  float* xp   = (float*)(ws + OFF_XP);
  u64*   maskT = (u64*)(ws + OFF_MASKT);
  u64*   maskd = (u64*)(ws + OFF_MASKD);
  float* x2   = (float*)(ws + OFF_X2);
  float* Wco  = (float*)(ws + OFF_WCO);
  float* bco  = (float*)(ws + OFF_BCO);
  float* logits = (float*)(ws + OFF_LOG);
  float* scores = (float*)(ws + OFF_SC);
  float* props  = (float*)(ws + OFF_PR);
  int*   order  = (int*)(ws + OFF_ORD);
  float* sb     = (float*)(ws + OFF_SB);

  // base anchors in double, rounded to f32 exactly like numpy
  BaseAnchors ba;
  {
    const double scales[3] = {64.0, 128.0, 256.0};
    const double ratios[3] = {0.5, 1.0, 2.0};
    int a = 0;
    for (int si = 0; si < 3; si++)
      for (int ri = 0; ri < 3; ri++, a++) {
        double w = scales[si] * sqrt(ratios[ri]);
        double h = scales[si] / sqrt(ratios[ri]);
        ba.x1[a] = (float)(-w / 2.0);
        ba.y1[a] = (float)(-h / 2.0);
        ba.x2[a] = (float)(w / 2.0);
        ba.y2[a] = (float)(h / 2.0);
      }
  }

  transpose_features<<<dim3(20, 16, 4), dim3(32, 8), 0, stream>>>(features, fm);
  transpose_weights<<<dim3(16, 16), 256, 0, stream>>>(conv_w, Wt);
  build_wco<<<128, 256, 0, stream>>>(cls_w, cls_b, bbox_w, bbox_b, Wco, bco);
  conv_gemm<<<dim3(40, 8, 3), 256, 0, stream>>>(fm, Wt, xp);
  combine_relu<<<1250, 256, 0, stream>>>(xp, conv_b, x2);
  gemm1x1<<<40, 256, 0, stream>>>(x2, Wco, bco, logits);
  score_box_kernel<<<88, 256, 0, stream>>>(logits, img_h, img_w, ba, scores, props);
  sort_kernel<<<4, 1024, 0, stream>>>(scores, props, order, sb);
  nms_mask_kernel<<<dim3(NW, NW, 4), 64, 0, stream>>>(sb, maskT, maskd);
  nms_scan_kernel<<<4, 1024, 0, stream>>>(maskT, maskd, order, sb, out);
}